// Round 3
// baseline (571.365 us; speedup 1.0000x reference)
//
#include <hip/hip_runtime.h>

// Problem constants (match reference setup_inputs()).
#define N_NODES 20000
#define E_EDGES 640000
// Layer dims: IN=256, H=8, HF=64, OUT=32

// ---------------------------------------------------------------------------
// CSR build: deg init (self-loop counts as 1), count, scan, scatter
// ---------------------------------------------------------------------------
__global__ __launch_bounds__(256) void init_deg_kernel(int* __restrict__ deg, int n) {
    int i = blockIdx.x * 256 + threadIdx.x;
    if (i < n) deg[i] = 1;  // every node gets exactly one self-loop
}

__global__ __launch_bounds__(256) void count_deg_kernel(const int* __restrict__ ei, int e,
                                                        int* __restrict__ deg) {
    int i = blockIdx.x * 256 + threadIdx.x;
    if (i < e) atomicAdd(&deg[ei[e + i]], 1);  // ei[1][i] = dst
}

__global__ __launch_bounds__(1024) void scan_kernel(const int* __restrict__ deg,
                                                    int* __restrict__ row_start,
                                                    int* __restrict__ cursor, int n) {
    __shared__ int wsum[16];
    __shared__ int carry_s;
    const int t = threadIdx.x;
    const int lane = t & 63;
    const int wv = t >> 6;
    int running = 0;
    for (int base = 0; base < n; base += 1024) {
        int idx = base + t;
        int v = (idx < n) ? deg[idx] : 0;
        int x = v;
        #pragma unroll
        for (int off = 1; off < 64; off <<= 1) {
            int y = __shfl_up(x, off, 64);
            if (lane >= off) x += y;
        }
        if (lane == 63) wsum[wv] = x;
        __syncthreads();
        if (wv == 0 && lane < 16) {
            int w = wsum[lane];
            int xx = w;
            #pragma unroll
            for (int off = 1; off < 16; off <<= 1) {
                int y = __shfl_up(xx, off, 64);
                if (lane >= off) xx += y;
            }
            wsum[lane] = xx - w;
            if (lane == 15) carry_s = xx;
        }
        __syncthreads();
        int excl = running + wsum[wv] + (x - v);
        if (idx < n) { row_start[idx] = excl; cursor[idx] = excl; }
        running += carry_s;
        __syncthreads();
    }
    if (t == 0) row_start[n] = running;
}

__global__ __launch_bounds__(256) void scatter_kernel(const int* __restrict__ ei, int e, int n,
                                                      int* __restrict__ cursor,
                                                      int* __restrict__ csr_src) {
    int i = blockIdx.x * 256 + threadIdx.x;
    if (i >= e + n) return;
    int s, d;
    if (i < e) { s = ei[i]; d = ei[e + i]; }
    else       { s = i - e; d = s; }       // self-loop
    int slot = atomicAdd(&cursor[d], 1);
    csr_src[slot] = s;
}

// ---------------------------------------------------------------------------
// fp32 tiled GEMM: C[M,N] = A[M,K] @ B[K,N].  K % 16 == 0, N % 64 == 0.
// ---------------------------------------------------------------------------
__global__ __launch_bounds__(256) void gemm_kernel(const float* __restrict__ A,
                                                   const float* __restrict__ B,
                                                   float* __restrict__ C,
                                                   int M, int K, int N) {
    __shared__ float As[16][68];
    __shared__ float Bs[16][64];
    const int t = threadIdx.x;
    const int bm = blockIdx.x * 64;
    const int bn = blockIdx.y * 64;
    const int tx = t & 15, ty = t >> 4;
    const int arow = t >> 2;
    const int acol4 = (t & 3) * 4;
    const int brow = t >> 4;
    const int bcol4 = (t & 15) * 4;

    float acc[4][4];
    #pragma unroll
    for (int i = 0; i < 4; ++i)
        #pragma unroll
        for (int j = 0; j < 4; ++j) acc[i][j] = 0.f;

    for (int k0 = 0; k0 < K; k0 += 16) {
        float4 av;
        if (bm + arow < M) av = *(const float4*)&A[(size_t)(bm + arow) * K + k0 + acol4];
        else               av = make_float4(0.f, 0.f, 0.f, 0.f);
        float4 bv = *(const float4*)&B[(size_t)(k0 + brow) * N + bn + bcol4];
        As[acol4 + 0][arow] = av.x;
        As[acol4 + 1][arow] = av.y;
        As[acol4 + 2][arow] = av.z;
        As[acol4 + 3][arow] = av.w;
        *(float4*)&Bs[brow][bcol4] = bv;
        __syncthreads();
        #pragma unroll
        for (int kk = 0; kk < 16; ++kk) {
            float4 a = *(const float4*)&As[kk][ty * 4];
            float4 b = *(const float4*)&Bs[kk][tx * 4];
            acc[0][0] += a.x * b.x; acc[0][1] += a.x * b.y; acc[0][2] += a.x * b.z; acc[0][3] += a.x * b.w;
            acc[1][0] += a.y * b.x; acc[1][1] += a.y * b.y; acc[1][2] += a.y * b.z; acc[1][3] += a.y * b.w;
            acc[2][0] += a.z * b.x; acc[2][1] += a.z * b.y; acc[2][2] += a.z * b.z; acc[2][3] += a.z * b.w;
            acc[3][0] += a.w * b.x; acc[3][1] += a.w * b.y; acc[3][2] += a.w * b.z; acc[3][3] += a.w * b.w;
        }
        __syncthreads();
    }
    #pragma unroll
    for (int i = 0; i < 4; ++i) {
        int r = bm + ty * 4 + i;
        if (r < M)
            *(float4*)&C[(size_t)r * N + bn + tx * 4] =
                make_float4(acc[i][0], acc[i][1], acc[i][2], acc[i][3]);
    }
}

// ---------------------------------------------------------------------------
// Per-node attention logits.
// ---------------------------------------------------------------------------
template <int CH>
__global__ __launch_bounds__(256) void logits_kernel(const float* __restrict__ h,
                                                     const float* __restrict__ att_src,
                                                     const float* __restrict__ att_dst,
                                                     float* __restrict__ asrc,
                                                     float* __restrict__ adst) {
    constexpr int F = 8 * CH;
    __shared__ float ss[F], sd[F];
    const int i = blockIdx.x, t = threadIdx.x;
    for (int f = t; f < F; f += 256) {
        float v = h[(size_t)i * F + f];
        ss[f] = v * att_src[f];
        sd[f] = v * att_dst[f];
    }
    __syncthreads();
    for (int off = CH / 2; off > 0; off >>= 1) {
        for (int f = t; f < F; f += 256) {
            if ((f & (CH - 1)) < off) { ss[f] += ss[f + off]; sd[f] += sd[f + off]; }
        }
        __syncthreads();
    }
    if (t < 8) {
        asrc[(size_t)i * 8 + t] = ss[t * CH];
        adst[(size_t)i * 8 + t] = sd[t * CH];
    }
}

// ---------------------------------------------------------------------------
// Per-dst-node softmax + weighted aggregation + head-mean + bias (+relu).
// v3: float4 gathers with edges split across wave groups (NSUB edges in
// flight per iter x unroll 4), MAXD=128 -> ~9.5 KB LDS -> 8 blocks/CU.
// One block (256 threads) per node.
// ---------------------------------------------------------------------------
template <int CH, bool RELU>
__global__ __launch_bounds__(256) void aggregate_kernel(const float* __restrict__ h,
                                                        const float* __restrict__ asrc,
                                                        const float* __restrict__ adst,
                                                        const int* __restrict__ row_start,
                                                        const int* __restrict__ csr_src,
                                                        const float* __restrict__ bias,
                                                        float* __restrict__ out) {
    constexpr int F = 8 * CH;            // 512 or 256
    constexpr int NSUB = 1024 / F;       // edges processed per iteration: 2 or 4
    constexpr int TPE = F / 4;           // threads per edge: 128 or 64
    constexpr int MAXD = 128;            // Poisson(32): max deg ~67; fallback below
    __shared__ int   s_src[MAXD];
    __shared__ float s_e[MAXD * 9];      // [k][9]: heads at +0..7, pad for banks
    __shared__ float s_m[8], s_dinv[8], s_adst[8];
    __shared__ float s_full[NSUB][F];
    const int i = blockIdx.x;
    const int tid = threadIdx.x;
    const int start = row_start[i];
    const int deg = row_start[i + 1] - start;
    const int head = tid >> 5;           // for phases 1-2: 32 threads per head
    const int lane = tid & 31;

    if (tid < 8) s_adst[tid] = adst[(size_t)i * 8 + tid];

    if (deg <= MAXD) {
        // ---- stage src indices ----
        if (tid < deg) s_src[tid] = csr_src[start + tid];
        __syncthreads();

        // ---- phase 1: e = leaky(asrc[src] + adst[dst]) into LDS ----
        {
            const int h8 = tid & 7;
            const float ad = s_adst[h8];
            for (int k = tid >> 3; k < deg; k += 32) {
                float e = asrc[(size_t)s_src[k] * 8 + h8] + ad;
                e = e > 0.f ? e : 0.2f * e;
                s_e[k * 9 + h8] = e;
            }
        }
        __syncthreads();

        // ---- phase 2: per-head max, then exp + sum (exp stored in-place) ----
        float mx = -1e30f;
        for (int k = lane; k < deg; k += 32) mx = fmaxf(mx, s_e[k * 9 + head]);
        #pragma unroll
        for (int off = 16; off > 0; off >>= 1) mx = fmaxf(mx, __shfl_down(mx, off, 32));
        if (lane == 0) s_m[head] = mx;
        __syncthreads();
        const float m_h = s_m[head];
        float sm = 0.f;
        for (int k = lane; k < deg; k += 32) {
            float ex = __expf(s_e[k * 9 + head] - m_h);
            s_e[k * 9 + head] = ex;
            sm += ex;
        }
        #pragma unroll
        for (int off = 16; off > 0; off >>= 1) sm += __shfl_down(sm, off, 32);
        if (lane == 0) s_dinv[head] = 1.0f / sm;
        __syncthreads();

        // ---- phase 3: weighted gather-accumulate, float4 per thread ----
        // Thread handles channels c0..c0+3 of edge subset {sub, sub+NSUB, ...}.
        const int sub = tid / TPE;             // wave-uniform
        const int c0 = (tid & (TPE - 1)) * 4;
        const int hc = c0 / CH;                // this thread's head
        float4 acc = make_float4(0.f, 0.f, 0.f, 0.f);
        int k = sub;
        for (; k + 3 * NSUB < deg; k += 4 * NSUB) {
            const int j0 = s_src[k];
            const int j1 = s_src[k + NSUB];
            const int j2 = s_src[k + 2 * NSUB];
            const int j3 = s_src[k + 3 * NSUB];
            const float w0 = s_e[(k) * 9 + hc];
            const float w1 = s_e[(k + NSUB) * 9 + hc];
            const float w2 = s_e[(k + 2 * NSUB) * 9 + hc];
            const float w3 = s_e[(k + 3 * NSUB) * 9 + hc];
            const float4 v0 = *(const float4*)&h[(size_t)j0 * F + c0];
            const float4 v1 = *(const float4*)&h[(size_t)j1 * F + c0];
            const float4 v2 = *(const float4*)&h[(size_t)j2 * F + c0];
            const float4 v3 = *(const float4*)&h[(size_t)j3 * F + c0];
            acc.x += w0 * v0.x; acc.y += w0 * v0.y; acc.z += w0 * v0.z; acc.w += w0 * v0.w;
            acc.x += w1 * v1.x; acc.y += w1 * v1.y; acc.z += w1 * v1.z; acc.w += w1 * v1.w;
            acc.x += w2 * v2.x; acc.y += w2 * v2.y; acc.z += w2 * v2.z; acc.w += w2 * v2.w;
            acc.x += w3 * v3.x; acc.y += w3 * v3.y; acc.z += w3 * v3.z; acc.w += w3 * v3.w;
        }
        for (; k < deg; k += NSUB) {
            const int j = s_src[k];
            const float w = s_e[k * 9 + hc];
            const float4 v = *(const float4*)&h[(size_t)j * F + c0];
            acc.x += w * v.x; acc.y += w * v.y; acc.z += w * v.z; acc.w += w * v.w;
        }
        *(float4*)&s_full[sub][c0] = acc;
        __syncthreads();
    } else {
        // ---- fallback slow path (deg > MAXD) ----
        float* s_red = s_e;  // alias scratch (>=256 floats)
        __syncthreads();

        float mx = -1e30f;
        for (int k = lane; k < deg; k += 32) {
            int j = csr_src[start + k];
            float e = asrc[(size_t)j * 8 + head] + s_adst[head];
            e = e > 0.f ? e : 0.2f * e;
            mx = fmaxf(mx, e);
        }
        s_red[tid] = mx;
        __syncthreads();
        #pragma unroll
        for (int off = 16; off > 0; off >>= 1) {
            if (lane < off) s_red[tid] = fmaxf(s_red[tid], s_red[tid + off]);
            __syncthreads();
        }
        if (lane == 0) s_m[head] = s_red[tid];
        __syncthreads();

        const float m_h = s_m[head];
        float sm = 0.f;
        for (int k = lane; k < deg; k += 32) {
            int j = csr_src[start + k];
            float e = asrc[(size_t)j * 8 + head] + s_adst[head];
            e = e > 0.f ? e : 0.2f * e;
            sm += __expf(e - m_h);
        }
        s_red[tid] = sm;
        __syncthreads();
        #pragma unroll
        for (int off = 16; off > 0; off >>= 1) {
            if (lane < off) s_red[tid] += s_red[tid + off];
            __syncthreads();
        }
        if (lane == 0) s_dinv[head] = 1.0f / s_red[tid];
        __syncthreads();

        constexpr int PER = F / 256;
        float acc[PER];
        int hh[PER];
        float mm[PER], dd[PER], aa[PER];
        #pragma unroll
        for (int p = 0; p < PER; ++p) {
            acc[p] = 0.f;
            int f = tid + p * 256;
            hh[p] = f / CH;
            mm[p] = s_m[hh[p]];
            dd[p] = s_dinv[hh[p]];
            aa[p] = s_adst[hh[p]];
        }
        for (int k = 0; k < deg; ++k) {
            int j = csr_src[start + k];
            const float* hj = h + (size_t)j * F;
            #pragma unroll
            for (int p = 0; p < PER; ++p) {
                float e = asrc[(size_t)j * 8 + hh[p]] + aa[p];
                e = e > 0.f ? e : 0.2f * e;
                float al = __expf(e - mm[p]) * dd[p];
                acc[p] += al * hj[tid + p * 256];
            }
        }
        __syncthreads();
        // alpha already includes dinv here; neutralize epilogue's dinv
        #pragma unroll
        for (int p = 0; p < PER; ++p) s_full[0][tid + p * 256] = acc[p];
        for (int sb = 1; sb < NSUB; ++sb)
            for (int f = tid; f < F; f += 256) s_full[sb][f] = 0.f;
        if (tid < 8) s_dinv[tid] = 1.0f;
        __syncthreads();
    }

    // ---- merge subsets, mean over heads + bias (+relu) ----
    if (tid < CH) {
        float v = 0.f;
        #pragma unroll
        for (int h8 = 0; h8 < 8; ++h8) {
            float t = 0.f;
            #pragma unroll
            for (int sb = 0; sb < NSUB; ++sb) t += s_full[sb][h8 * CH + tid];
            v += t * s_dinv[h8];
        }
        v = v * 0.125f + bias[tid];
        if (RELU) v = fmaxf(v, 0.f);
        out[(size_t)i * CH + tid] = v;
    }
}

// ---------------------------------------------------------------------------
// Launch
// ---------------------------------------------------------------------------
extern "C" void kernel_launch(void* const* d_in, const int* in_sizes, int n_in,
                              void* d_out, int out_size, void* d_ws, size_t ws_size,
                              hipStream_t stream) {
    const float* x   = (const float*)d_in[0];
    const int*   ei  = (const int*)d_in[1];
    const float* W1  = (const float*)d_in[2];
    const float* as1 = (const float*)d_in[3];
    const float* ad1 = (const float*)d_in[4];
    const float* b1  = (const float*)d_in[5];
    const float* W2  = (const float*)d_in[6];
    const float* as2 = (const float*)d_in[7];
    const float* ad2 = (const float*)d_in[8];
    const float* b2  = (const float*)d_in[9];
    float* out = (float*)d_out;

    const int n = N_NODES;
    const int e = E_EDGES;

    // workspace layout
    char* w = (char*)d_ws;
    float* h_buf = (float*)w; w += (size_t)n * 512 * 4;   // h1 then reused for h2
    float* y1    = (float*)w; w += (size_t)n * 64 * 4;
    float* asrc  = (float*)w; w += (size_t)n * 8 * 4;
    float* adst  = (float*)w; w += (size_t)n * 8 * 4;
    int* deg       = (int*)w; w += (size_t)n * 4;
    int* row_start = (int*)w; w += (size_t)(n + 1) * 4;
    int* cursor    = (int*)w; w += (size_t)n * 4;
    int* csr_src   = (int*)w; w += (size_t)(e + n) * 4;

    // ---- CSR build (graph identical for both layers) ----
    init_deg_kernel<<<(n + 255) / 256, 256, 0, stream>>>(deg, n);
    count_deg_kernel<<<(e + 255) / 256, 256, 0, stream>>>(ei, e, deg);
    scan_kernel<<<1, 1024, 0, stream>>>(deg, row_start, cursor, n);
    scatter_kernel<<<(e + n + 255) / 256, 256, 0, stream>>>(ei, e, n, cursor, csr_src);

    const int mblocks = (n + 63) / 64;  // 313

    // ---- Layer 1 ----
    gemm_kernel<<<dim3(mblocks, 8), 256, 0, stream>>>(x, W1, h_buf, n, 256, 512);
    logits_kernel<64><<<n, 256, 0, stream>>>(h_buf, as1, ad1, asrc, adst);
    aggregate_kernel<64, true><<<n, 256, 0, stream>>>(h_buf, asrc, adst, row_start,
                                                      csr_src, b1, y1);

    // ---- Layer 2 ----
    gemm_kernel<<<dim3(mblocks, 4), 256, 0, stream>>>(y1, W2, h_buf, n, 64, 256);
    logits_kernel<32><<<n, 256, 0, stream>>>(h_buf, as2, ad2, asrc, adst);
    aggregate_kernel<32, false><<<n, 256, 0, stream>>>(h_buf, asrc, adst, row_start,
                                                       csr_src, b2, out);
}

// Round 4
// 437.264 us; speedup vs baseline: 1.3067x; 1.3067x over previous
//
#include <hip/hip_runtime.h>
#include <hip/hip_fp16.h>

// Problem constants (match reference setup_inputs()).
#define N_NODES 20000
#define E_EDGES 640000
// Layer dims: IN=256, H=8, HF=64, OUT=32

// ---------------------------------------------------------------------------
// CSR build: deg init (self-loop counts as 1), count, scan, scatter
// ---------------------------------------------------------------------------
__global__ __launch_bounds__(256) void init_deg_kernel(int* __restrict__ deg, int n) {
    int i = blockIdx.x * 256 + threadIdx.x;
    if (i < n) deg[i] = 1;  // every node gets exactly one self-loop
}

__global__ __launch_bounds__(256) void count_deg_kernel(const int* __restrict__ ei, int e,
                                                        int* __restrict__ deg) {
    int i = blockIdx.x * 256 + threadIdx.x;
    if (i < e) atomicAdd(&deg[ei[e + i]], 1);  // ei[1][i] = dst
}

__global__ __launch_bounds__(1024) void scan_kernel(const int* __restrict__ deg,
                                                    int* __restrict__ row_start,
                                                    int* __restrict__ cursor, int n) {
    __shared__ int wsum[16];
    __shared__ int carry_s;
    const int t = threadIdx.x;
    const int lane = t & 63;
    const int wv = t >> 6;
    int running = 0;
    for (int base = 0; base < n; base += 1024) {
        int idx = base + t;
        int v = (idx < n) ? deg[idx] : 0;
        int x = v;
        #pragma unroll
        for (int off = 1; off < 64; off <<= 1) {
            int y = __shfl_up(x, off, 64);
            if (lane >= off) x += y;
        }
        if (lane == 63) wsum[wv] = x;
        __syncthreads();
        if (wv == 0 && lane < 16) {
            int w = wsum[lane];
            int xx = w;
            #pragma unroll
            for (int off = 1; off < 16; off <<= 1) {
                int y = __shfl_up(xx, off, 64);
                if (lane >= off) xx += y;
            }
            wsum[lane] = xx - w;
            if (lane == 15) carry_s = xx;
        }
        __syncthreads();
        int excl = running + wsum[wv] + (x - v);
        if (idx < n) { row_start[idx] = excl; cursor[idx] = excl; }
        running += carry_s;
        __syncthreads();
    }
    if (t == 0) row_start[n] = running;
}

__global__ __launch_bounds__(256) void scatter_kernel(const int* __restrict__ ei, int e, int n,
                                                      int* __restrict__ cursor,
                                                      int* __restrict__ csr_src) {
    int i = blockIdx.x * 256 + threadIdx.x;
    if (i >= e + n) return;
    int s, d;
    if (i < e) { s = ei[i]; d = ei[e + i]; }
    else       { s = i - e; d = s; }       // self-loop
    int slot = atomicAdd(&cursor[d], 1);
    csr_src[slot] = s;
}

// ---------------------------------------------------------------------------
// fp32 tiled GEMM, fp16 output: C[M,N] = A[M,K] @ B[K,N].
// K % 16 == 0, N % 64 == 0.  Math in fp32, store as __half.
// ---------------------------------------------------------------------------
__global__ __launch_bounds__(256) void gemm_kernel(const float* __restrict__ A,
                                                   const float* __restrict__ B,
                                                   __half* __restrict__ C,
                                                   int M, int K, int N) {
    __shared__ float As[16][68];
    __shared__ float Bs[16][64];
    const int t = threadIdx.x;
    const int bm = blockIdx.x * 64;
    const int bn = blockIdx.y * 64;
    const int tx = t & 15, ty = t >> 4;
    const int arow = t >> 2;
    const int acol4 = (t & 3) * 4;
    const int brow = t >> 4;
    const int bcol4 = (t & 15) * 4;

    float acc[4][4];
    #pragma unroll
    for (int i = 0; i < 4; ++i)
        #pragma unroll
        for (int j = 0; j < 4; ++j) acc[i][j] = 0.f;

    for (int k0 = 0; k0 < K; k0 += 16) {
        float4 av;
        if (bm + arow < M) av = *(const float4*)&A[(size_t)(bm + arow) * K + k0 + acol4];
        else               av = make_float4(0.f, 0.f, 0.f, 0.f);
        float4 bv = *(const float4*)&B[(size_t)(k0 + brow) * N + bn + bcol4];
        As[acol4 + 0][arow] = av.x;
        As[acol4 + 1][arow] = av.y;
        As[acol4 + 2][arow] = av.z;
        As[acol4 + 3][arow] = av.w;
        *(float4*)&Bs[brow][bcol4] = bv;
        __syncthreads();
        #pragma unroll
        for (int kk = 0; kk < 16; ++kk) {
            float4 a = *(const float4*)&As[kk][ty * 4];
            float4 b = *(const float4*)&Bs[kk][tx * 4];
            acc[0][0] += a.x * b.x; acc[0][1] += a.x * b.y; acc[0][2] += a.x * b.z; acc[0][3] += a.x * b.w;
            acc[1][0] += a.y * b.x; acc[1][1] += a.y * b.y; acc[1][2] += a.y * b.z; acc[1][3] += a.y * b.w;
            acc[2][0] += a.z * b.x; acc[2][1] += a.z * b.y; acc[2][2] += a.z * b.z; acc[2][3] += a.z * b.w;
            acc[3][0] += a.w * b.x; acc[3][1] += a.w * b.y; acc[3][2] += a.w * b.z; acc[3][3] += a.w * b.w;
        }
        __syncthreads();
    }
    #pragma unroll
    for (int i = 0; i < 4; ++i) {
        int r = bm + ty * 4 + i;
        if (r < M) {
            union { __half h[4]; uint2 u; } pk;
            pk.h[0] = __float2half(acc[i][0]);
            pk.h[1] = __float2half(acc[i][1]);
            pk.h[2] = __float2half(acc[i][2]);
            pk.h[3] = __float2half(acc[i][3]);
            *(uint2*)&C[(size_t)r * N + bn + tx * 4] = pk.u;
        }
    }
}

// ---------------------------------------------------------------------------
// Per-node attention logits (fp16 h input, fp32 logits out).
// ---------------------------------------------------------------------------
template <int CH>
__global__ __launch_bounds__(256) void logits_kernel(const __half* __restrict__ h,
                                                     const float* __restrict__ att_src,
                                                     const float* __restrict__ att_dst,
                                                     float* __restrict__ asrc,
                                                     float* __restrict__ adst) {
    constexpr int F = 8 * CH;
    __shared__ float ss[F], sd[F];
    const int i = blockIdx.x, t = threadIdx.x;
    for (int f = t; f < F; f += 256) {
        float v = __half2float(h[(size_t)i * F + f]);
        ss[f] = v * att_src[f];
        sd[f] = v * att_dst[f];
    }
    __syncthreads();
    for (int off = CH / 2; off > 0; off >>= 1) {
        for (int f = t; f < F; f += 256) {
            if ((f & (CH - 1)) < off) { ss[f] += ss[f + off]; sd[f] += sd[f + off]; }
        }
        __syncthreads();
    }
    if (t < 8) {
        asrc[(size_t)i * 8 + t] = ss[t * CH];
        adst[(size_t)i * 8 + t] = sd[t * CH];
    }
}

// ---------------------------------------------------------------------------
// Per-dst-node softmax + weighted aggregation + head-mean + bias (+relu).
// v4: h gathered as fp16 (16 B = 8 halves per thread), fp32 accumulate.
// NSUB edges in flight (4 for CH=64, 8 for CH=32), unroll x4.
// One block (256 threads) per node.
// ---------------------------------------------------------------------------
template <int CH, bool RELU>
__global__ __launch_bounds__(256) void aggregate_kernel(const __half* __restrict__ h,
                                                        const float* __restrict__ asrc,
                                                        const float* __restrict__ adst,
                                                        const int* __restrict__ row_start,
                                                        const int* __restrict__ csr_src,
                                                        const float* __restrict__ bias,
                                                        float* __restrict__ out) {
    constexpr int F = 8 * CH;            // 512 or 256 (halves per row)
    constexpr int TPE = F / 8;           // threads per edge: 64 or 32
    constexpr int NSUB = 256 / TPE;      // edges in flight: 4 or 8
    constexpr int MAXD = 128;            // Poisson(32): max deg ~67; fallback below
    __shared__ int   s_src[MAXD];
    __shared__ float s_e[MAXD * 9];      // [k][9]: heads at +0..7, pad for banks
    __shared__ float s_m[8], s_dinv[8], s_adst[8];
    __shared__ float s_full[NSUB][F];
    const int i = blockIdx.x;
    const int tid = threadIdx.x;
    const int start = row_start[i];
    const int deg = row_start[i + 1] - start;
    const int head = tid >> 5;           // for phases 1-2: 32 threads per head
    const int lane = tid & 31;

    if (tid < 8) s_adst[tid] = adst[(size_t)i * 8 + tid];

    if (deg <= MAXD) {
        // ---- stage src indices ----
        if (tid < deg) s_src[tid] = csr_src[start + tid];
        __syncthreads();

        // ---- phase 1: e = leaky(asrc[src] + adst[dst]) into LDS ----
        {
            const int h8 = tid & 7;
            const float ad = s_adst[h8];
            for (int k = tid >> 3; k < deg; k += 32) {
                float e = asrc[(size_t)s_src[k] * 8 + h8] + ad;
                e = e > 0.f ? e : 0.2f * e;
                s_e[k * 9 + h8] = e;
            }
        }
        __syncthreads();

        // ---- phase 2: per-head max, then exp + sum (exp stored in-place) ----
        float mx = -1e30f;
        for (int k = lane; k < deg; k += 32) mx = fmaxf(mx, s_e[k * 9 + head]);
        #pragma unroll
        for (int off = 16; off > 0; off >>= 1) mx = fmaxf(mx, __shfl_down(mx, off, 32));
        if (lane == 0) s_m[head] = mx;
        __syncthreads();
        const float m_h = s_m[head];
        float sm = 0.f;
        for (int k = lane; k < deg; k += 32) {
            float ex = __expf(s_e[k * 9 + head] - m_h);
            s_e[k * 9 + head] = ex;
            sm += ex;
        }
        #pragma unroll
        for (int off = 16; off > 0; off >>= 1) sm += __shfl_down(sm, off, 32);
        if (lane == 0) s_dinv[head] = 1.0f / sm;
        __syncthreads();

        // ---- phase 3: weighted gather-accumulate, 8 halves per thread ----
        const int sub = tid / TPE;              // wave-uniform
        const int c0 = (tid & (TPE - 1)) * 8;   // first of 8 half-channels
        const int hc = c0 / CH;                 // this thread's head
        float acc[8];
        #pragma unroll
        for (int c = 0; c < 8; ++c) acc[c] = 0.f;
        union U16x8 { uint4 u; __half h[8]; };
        int k = sub;
        for (; k + 3 * NSUB < deg; k += 4 * NSUB) {
            const int j0 = s_src[k];
            const int j1 = s_src[k + NSUB];
            const int j2 = s_src[k + 2 * NSUB];
            const int j3 = s_src[k + 3 * NSUB];
            const float w0 = s_e[(k) * 9 + hc];
            const float w1 = s_e[(k + NSUB) * 9 + hc];
            const float w2 = s_e[(k + 2 * NSUB) * 9 + hc];
            const float w3 = s_e[(k + 3 * NSUB) * 9 + hc];
            U16x8 v0, v1, v2, v3;
            v0.u = *(const uint4*)&h[(size_t)j0 * F + c0];
            v1.u = *(const uint4*)&h[(size_t)j1 * F + c0];
            v2.u = *(const uint4*)&h[(size_t)j2 * F + c0];
            v3.u = *(const uint4*)&h[(size_t)j3 * F + c0];
            #pragma unroll
            for (int c = 0; c < 8; ++c) {
                acc[c] += w0 * __half2float(v0.h[c]);
                acc[c] += w1 * __half2float(v1.h[c]);
                acc[c] += w2 * __half2float(v2.h[c]);
                acc[c] += w3 * __half2float(v3.h[c]);
            }
        }
        for (; k < deg; k += NSUB) {
            const int j = s_src[k];
            const float w = s_e[k * 9 + hc];
            U16x8 v;
            v.u = *(const uint4*)&h[(size_t)j * F + c0];
            #pragma unroll
            for (int c = 0; c < 8; ++c) acc[c] += w * __half2float(v.h[c]);
        }
        *(float4*)&s_full[sub][c0] = make_float4(acc[0], acc[1], acc[2], acc[3]);
        *(float4*)&s_full[sub][c0 + 4] = make_float4(acc[4], acc[5], acc[6], acc[7]);
        __syncthreads();
    } else {
        // ---- fallback slow path (deg > MAXD) ----
        float* s_red = s_e;  // alias scratch (>=256 floats)
        __syncthreads();

        float mx = -1e30f;
        for (int k = lane; k < deg; k += 32) {
            int j = csr_src[start + k];
            float e = asrc[(size_t)j * 8 + head] + s_adst[head];
            e = e > 0.f ? e : 0.2f * e;
            mx = fmaxf(mx, e);
        }
        s_red[tid] = mx;
        __syncthreads();
        #pragma unroll
        for (int off = 16; off > 0; off >>= 1) {
            if (lane < off) s_red[tid] = fmaxf(s_red[tid], s_red[tid + off]);
            __syncthreads();
        }
        if (lane == 0) s_m[head] = s_red[tid];
        __syncthreads();

        const float m_h = s_m[head];
        float sm = 0.f;
        for (int k = lane; k < deg; k += 32) {
            int j = csr_src[start + k];
            float e = asrc[(size_t)j * 8 + head] + s_adst[head];
            e = e > 0.f ? e : 0.2f * e;
            sm += __expf(e - m_h);
        }
        s_red[tid] = sm;
        __syncthreads();
        #pragma unroll
        for (int off = 16; off > 0; off >>= 1) {
            if (lane < off) s_red[tid] += s_red[tid + off];
            __syncthreads();
        }
        if (lane == 0) s_dinv[head] = 1.0f / s_red[tid];
        __syncthreads();

        constexpr int PER = F / 256;
        float acc[PER];
        int hh[PER];
        float mm[PER], dd[PER], aa[PER];
        #pragma unroll
        for (int p = 0; p < PER; ++p) {
            acc[p] = 0.f;
            int f = tid + p * 256;
            hh[p] = f / CH;
            mm[p] = s_m[hh[p]];
            dd[p] = s_dinv[hh[p]];
            aa[p] = s_adst[hh[p]];
        }
        for (int k = 0; k < deg; ++k) {
            int j = csr_src[start + k];
            const __half* hj = h + (size_t)j * F;
            #pragma unroll
            for (int p = 0; p < PER; ++p) {
                float e = asrc[(size_t)j * 8 + hh[p]] + aa[p];
                e = e > 0.f ? e : 0.2f * e;
                float al = __expf(e - mm[p]) * dd[p];
                acc[p] += al * __half2float(hj[tid + p * 256]);
            }
        }
        __syncthreads();
        // alpha already includes dinv here; neutralize epilogue's dinv
        #pragma unroll
        for (int p = 0; p < PER; ++p) s_full[0][tid + p * 256] = acc[p];
        for (int sb = 1; sb < NSUB; ++sb)
            for (int f = tid; f < F; f += 256) s_full[sb][f] = 0.f;
        if (tid < 8) s_dinv[tid] = 1.0f;
        __syncthreads();
    }

    // ---- merge subsets, mean over heads + bias (+relu) ----
    if (tid < CH) {
        float v = 0.f;
        #pragma unroll
        for (int h8 = 0; h8 < 8; ++h8) {
            float t = 0.f;
            #pragma unroll
            for (int sb = 0; sb < NSUB; ++sb) t += s_full[sb][h8 * CH + tid];
            v += t * s_dinv[h8];
        }
        v = v * 0.125f + bias[tid];
        if (RELU) v = fmaxf(v, 0.f);
        out[(size_t)i * CH + tid] = v;
    }
}

// ---------------------------------------------------------------------------
// Launch
// ---------------------------------------------------------------------------
extern "C" void kernel_launch(void* const* d_in, const int* in_sizes, int n_in,
                              void* d_out, int out_size, void* d_ws, size_t ws_size,
                              hipStream_t stream) {
    const float* x   = (const float*)d_in[0];
    const int*   ei  = (const int*)d_in[1];
    const float* W1  = (const float*)d_in[2];
    const float* as1 = (const float*)d_in[3];
    const float* ad1 = (const float*)d_in[4];
    const float* b1  = (const float*)d_in[5];
    const float* W2  = (const float*)d_in[6];
    const float* as2 = (const float*)d_in[7];
    const float* ad2 = (const float*)d_in[8];
    const float* b2  = (const float*)d_in[9];
    float* out = (float*)d_out;

    const int n = N_NODES;
    const int e = E_EDGES;

    // workspace layout
    char* w = (char*)d_ws;
    __half* h_buf = (__half*)w; w += (size_t)n * 512 * 2;  // h1 (fp16), reused for h2
    float* y1    = (float*)w; w += (size_t)n * 64 * 4;
    float* asrc  = (float*)w; w += (size_t)n * 8 * 4;
    float* adst  = (float*)w; w += (size_t)n * 8 * 4;
    int* deg       = (int*)w; w += (size_t)n * 4;
    int* row_start = (int*)w; w += (size_t)(n + 1) * 4;
    int* cursor    = (int*)w; w += (size_t)n * 4;
    int* csr_src   = (int*)w; w += (size_t)(e + n) * 4;

    // ---- CSR build (graph identical for both layers) ----
    init_deg_kernel<<<(n + 255) / 256, 256, 0, stream>>>(deg, n);
    count_deg_kernel<<<(e + 255) / 256, 256, 0, stream>>>(ei, e, deg);
    scan_kernel<<<1, 1024, 0, stream>>>(deg, row_start, cursor, n);
    scatter_kernel<<<(e + n + 255) / 256, 256, 0, stream>>>(ei, e, n, cursor, csr_src);

    const int mblocks = (n + 63) / 64;  // 313

    // ---- Layer 1 ----
    gemm_kernel<<<dim3(mblocks, 8), 256, 0, stream>>>(x, W1, h_buf, n, 256, 512);
    logits_kernel<64><<<n, 256, 0, stream>>>(h_buf, as1, ad1, asrc, adst);
    aggregate_kernel<64, true><<<n, 256, 0, stream>>>(h_buf, asrc, adst, row_start,
                                                      csr_src, b1, y1);

    // ---- Layer 2 ----
    gemm_kernel<<<dim3(mblocks, 4), 256, 0, stream>>>(y1, W2, h_buf, n, 64, 256);
    logits_kernel<32><<<n, 256, 0, stream>>>(h_buf, as2, ad2, asrc, adst);
    aggregate_kernel<32, false><<<n, 256, 0, stream>>>(h_buf, asrc, adst, row_start,
                                                       csr_src, b2, out);
}

// Round 5
// 398.701 us; speedup vs baseline: 1.4331x; 1.0967x over previous
//
#include <hip/hip_runtime.h>
#include <hip/hip_fp16.h>

// Problem constants (match reference setup_inputs()).
#define N_NODES 20000
#define E_EDGES 640000
// Layer dims: IN=256, H=8, HF=64, OUT=32

using half8_t = __attribute__((ext_vector_type(8))) _Float16;
using f32x4   = __attribute__((ext_vector_type(4))) float;

// ---------------------------------------------------------------------------
// CSR build: deg init (self-loop counts as 1), count, scan, scatter
// ---------------------------------------------------------------------------
__global__ __launch_bounds__(256) void init_deg_kernel(int* __restrict__ deg, int n) {
    int i = blockIdx.x * 256 + threadIdx.x;
    if (i < n) deg[i] = 1;
}

__global__ __launch_bounds__(256) void count_deg_kernel(const int* __restrict__ ei, int e,
                                                        int* __restrict__ deg) {
    int i = blockIdx.x * 256 + threadIdx.x;
    if (i < e) atomicAdd(&deg[ei[e + i]], 1);  // ei[1][i] = dst
}

__global__ __launch_bounds__(1024) void scan_kernel(const int* __restrict__ deg,
                                                    int* __restrict__ row_start,
                                                    int* __restrict__ cursor, int n) {
    __shared__ int wsum[16];
    __shared__ int carry_s;
    const int t = threadIdx.x;
    const int lane = t & 63;
    const int wv = t >> 6;
    int running = 0;
    for (int base = 0; base < n; base += 1024) {
        int idx = base + t;
        int v = (idx < n) ? deg[idx] : 0;
        int x = v;
        #pragma unroll
        for (int off = 1; off < 64; off <<= 1) {
            int y = __shfl_up(x, off, 64);
            if (lane >= off) x += y;
        }
        if (lane == 63) wsum[wv] = x;
        __syncthreads();
        if (wv == 0 && lane < 16) {
            int w = wsum[lane];
            int xx = w;
            #pragma unroll
            for (int off = 1; off < 16; off <<= 1) {
                int y = __shfl_up(xx, off, 64);
                if (lane >= off) xx += y;
            }
            wsum[lane] = xx - w;
            if (lane == 15) carry_s = xx;
        }
        __syncthreads();
        int excl = running + wsum[wv] + (x - v);
        if (idx < n) { row_start[idx] = excl; cursor[idx] = excl; }
        running += carry_s;
        __syncthreads();
    }
    if (t == 0) row_start[n] = running;
}

__global__ __launch_bounds__(256) void scatter_kernel(const int* __restrict__ ei, int e, int n,
                                                      int* __restrict__ cursor,
                                                      int* __restrict__ csr_src) {
    int i = blockIdx.x * 256 + threadIdx.x;
    if (i >= e + n) return;
    int s, d;
    if (i < e) { s = ei[i]; d = ei[e + i]; }
    else       { s = i - e; d = s; }       // self-loop
    int slot = atomicAdd(&cursor[d], 1);
    csr_src[slot] = s;
}

// ---------------------------------------------------------------------------
// Cast kernels: x -> fp16; W -> fp16 transposed (rows = output col, cols = k)
// ---------------------------------------------------------------------------
__global__ __launch_bounds__(256) void cast_x_kernel(const float* __restrict__ x,
                                                     __half* __restrict__ xh, int total8) {
    int t = blockIdx.x * 256 + threadIdx.x;
    if (t >= total8) return;
    size_t o = (size_t)t * 8;
    float4 a = *(const float4*)&x[o];
    float4 b = *(const float4*)&x[o + 4];
    union { __half h[8]; uint4 u; } pk;
    pk.h[0] = __float2half(a.x); pk.h[1] = __float2half(a.y);
    pk.h[2] = __float2half(a.z); pk.h[3] = __float2half(a.w);
    pk.h[4] = __float2half(b.x); pk.h[5] = __float2half(b.y);
    pk.h[6] = __float2half(b.z); pk.h[7] = __float2half(b.w);
    *(uint4*)&xh[o] = pk.u;
}

// W[K][N] -> Wt[N][K] fp16.  grid.x = N, block = 256 (K <= 256 assumed per call)
__global__ __launch_bounds__(256) void cast_wt_kernel(const float* __restrict__ W,
                                                      __half* __restrict__ Wt, int K, int N) {
    int nrow = blockIdx.x;
    int k = threadIdx.x;
    if (k < K) Wt[(size_t)nrow * K + k] = __float2half(W[(size_t)k * N + nrow]);
}

// ---------------------------------------------------------------------------
// fp16 MFMA GEMM: C[M,N] = A[M,K] @ B[K,N], B given TRANSPOSED as Bt[N][K].
// fp16 in, fp16 out, fp32 accumulate. K % 32 == 0, N % 64 == 0.
// 64x64 tile, 256 threads = 4 waves; wave w does rows w*16..w*16+15, all 4
// col-tiles via v_mfma_f32_16x16x32_f16.
// Fragment layouts (cdna4 guide, m89/m120-verified):
//   A frag: lane holds A[m=lane&15][k=quad*8+j], j=0..7
//   B frag: lane holds B[k=quad*8+j][n=lane&15]  == Bt row (n), contiguous k
//   C/D   : reg r -> row=quad*4+r, col=lane&15
// ---------------------------------------------------------------------------
__global__ __launch_bounds__(256) void gemm_f16_kernel(const __half* __restrict__ A,
                                                       const __half* __restrict__ Bt,
                                                       __half* __restrict__ C,
                                                       int M, int K, int N) {
    constexpr int LDT = 40;  // LDS row stride in halves (32 + 8 pad)
    __shared__ __align__(16) _Float16 As[64 * LDT];
    __shared__ __align__(16) _Float16 Bs[64 * LDT];
    const int tid = threadIdx.x;
    const int bm = blockIdx.x * 64;
    const int bn = blockIdx.y * 64;
    const int w = tid >> 6;
    const int lane = tid & 63;
    const int l16 = lane & 15;
    const int quad = lane >> 4;
    const int srow = tid >> 2;        // staging row 0..63
    const int skg = tid & 3;          // staging k-group (8 halves each)

    f32x4 acc[4];
    #pragma unroll
    for (int c = 0; c < 4; ++c) acc[c] = (f32x4){0.f, 0.f, 0.f, 0.f};

    for (int k0 = 0; k0 < K; k0 += 32) {
        // stage A tile [64][32] and Bt tile [64][32]
        uint4 av = make_uint4(0, 0, 0, 0);
        if (bm + srow < M) av = *(const uint4*)&A[(size_t)(bm + srow) * K + k0 + skg * 8];
        uint4 bv = *(const uint4*)&Bt[(size_t)(bn + srow) * K + k0 + skg * 8];
        *(uint4*)&As[srow * LDT + skg * 8] = av;
        *(uint4*)&Bs[srow * LDT + skg * 8] = bv;
        __syncthreads();

        half8_t af = *(const half8_t*)&As[(w * 16 + l16) * LDT + quad * 8];
        #pragma unroll
        for (int c = 0; c < 4; ++c) {
            half8_t bf = *(const half8_t*)&Bs[(c * 16 + l16) * LDT + quad * 8];
            acc[c] = __builtin_amdgcn_mfma_f32_16x16x32_f16(af, bf, acc[c], 0, 0, 0);
        }
        __syncthreads();
    }

    #pragma unroll
    for (int c = 0; c < 4; ++c) {
        #pragma unroll
        for (int r = 0; r < 4; ++r) {
            int row = bm + w * 16 + quad * 4 + r;
            if (row < M)
                C[(size_t)row * N + bn + c * 16 + l16] = __float2half(acc[c][r]);
        }
    }
}

// ---------------------------------------------------------------------------
// Per-node attention logits (fp16 h). One wave per node, 4 nodes per block.
// ---------------------------------------------------------------------------
template <int CH>
__global__ __launch_bounds__(256) void logits_kernel(const __half* __restrict__ h,
                                                     const float* __restrict__ att_src,
                                                     const float* __restrict__ att_dst,
                                                     float* __restrict__ asrc,
                                                     float* __restrict__ adst) {
    constexpr int F = 8 * CH;
    constexpr int J = F / 64;        // halves per lane: 8 (CH=64) or 4 (CH=32)
    const int tid = threadIdx.x;
    const int i = blockIdx.x * 4 + (tid >> 6);
    const int lane = tid & 63;
    const size_t hoff = (size_t)i * F + lane * J;
    float ps = 0.f, pd = 0.f;
    if (J == 8) {
        uint4 hv = *(const uint4*)&h[hoff];
        const __half* hp = (const __half*)&hv;
        #pragma unroll
        for (int j = 0; j < 8; ++j) {
            float v = __half2float(hp[j]);
            ps += v * att_src[lane * 8 + j];
            pd += v * att_dst[lane * 8 + j];
        }
    } else {
        uint2 hv = *(const uint2*)&h[hoff];
        const __half* hp = (const __half*)&hv;
        #pragma unroll
        for (int j = 0; j < 4; ++j) {
            float v = __half2float(hp[j]);
            ps += v * att_src[lane * 4 + j];
            pd += v * att_dst[lane * 4 + j];
        }
    }
    // 8 lanes per head in both cases; reduce within 8-lane groups
    #pragma unroll
    for (int off = 4; off; off >>= 1) {
        ps += __shfl_down(ps, off, 64);
        pd += __shfl_down(pd, off, 64);
    }
    if ((lane & 7) == 0) {
        asrc[(size_t)i * 8 + (lane >> 3)] = ps;
        adst[(size_t)i * 8 + (lane >> 3)] = pd;
    }
}

// ---------------------------------------------------------------------------
// Aggregation v5: one WAVE per (dst, head).  blockIdx = dst*8 + head, so with
// round-robin block->XCD dispatch all blocks of head h land on XCD h; each
// XCD's h-slice working set = N * CH*2B = 2.56 MB (CH=64) -> L2-resident.
// Writes fp32 partial[i][head][c] (softmax-weighted sum, no /8, no bias).
// ---------------------------------------------------------------------------
template <int CH>
__global__ __launch_bounds__(64) void aggregate_kernel(const __half* __restrict__ h,
                                                       const float* __restrict__ asrc,
                                                       const float* __restrict__ adst,
                                                       const int* __restrict__ row_start,
                                                       const int* __restrict__ csr_src,
                                                       float* __restrict__ partial) {
    constexpr int F = 8 * CH;
    constexpr int TPE = CH / 8;          // lanes per edge: 8 (CH=64) / 4 (CH=32)
    constexpr int NSUB = 64 / TPE;       // edges in flight: 8 / 16
    constexpr int MAXD = 128;
    __shared__ int   s_src[MAXD];
    __shared__ float s_e[MAXD];
    const int b = blockIdx.x;
    const int head = b & 7;
    const int i = b >> 3;
    const int lane = threadIdx.x;
    const int start = row_start[i];
    const int deg = row_start[i + 1] - start;
    const float ad = adst[(size_t)i * 8 + head];

    const int sub = lane / TPE;
    const int c0 = (lane % TPE) * 8;
    float acc[8];
    #pragma unroll
    for (int c = 0; c < 8; ++c) acc[c] = 0.f;
    float dinv;

    if (deg <= MAXD) {
        // phase 1: stage src + e, track max
        float mx = -1e30f;
        for (int k = lane; k < deg; k += 64) {
            int j = csr_src[start + k];
            s_src[k] = j;
            float e = asrc[(size_t)j * 8 + head] + ad;
            e = e > 0.f ? e : 0.2f * e;
            s_e[k] = e;
            mx = fmaxf(mx, e);
        }
        #pragma unroll
        for (int off = 32; off; off >>= 1) mx = fmaxf(mx, __shfl_down(mx, off, 64));
        mx = __shfl(mx, 0, 64);
        __syncthreads();
        // phase 2: exp in place + sum
        float sm = 0.f;
        for (int k = lane; k < deg; k += 64) {
            float ex = __expf(s_e[k] - mx);
            s_e[k] = ex;
            sm += ex;
        }
        #pragma unroll
        for (int off = 32; off; off >>= 1) sm += __shfl_down(sm, off, 64);
        dinv = 1.0f / __shfl(sm, 0, 64);
        __syncthreads();
        // phase 3: gather head-slice (16 B per lane per edge)
        for (int k = sub; k < deg; k += NSUB) {
            const int j = s_src[k];
            const float wgt = s_e[k];
            uint4 v = *(const uint4*)&h[(size_t)j * F + head * CH + c0];
            const __half* hv = (const __half*)&v;
            #pragma unroll
            for (int c = 0; c < 8; ++c) acc[c] += wgt * __half2float(hv[c]);
        }
    } else {
        // fallback (deg > MAXD): streaming recompute, no LDS cache
        float mx = -1e30f;
        for (int k = lane; k < deg; k += 64) {
            int j = csr_src[start + k];
            float e = asrc[(size_t)j * 8 + head] + ad;
            e = e > 0.f ? e : 0.2f * e;
            mx = fmaxf(mx, e);
        }
        #pragma unroll
        for (int off = 32; off; off >>= 1) mx = fmaxf(mx, __shfl_down(mx, off, 64));
        mx = __shfl(mx, 0, 64);
        float sm = 0.f;
        for (int k = lane; k < deg; k += 64) {
            int j = csr_src[start + k];
            float e = asrc[(size_t)j * 8 + head] + ad;
            e = e > 0.f ? e : 0.2f * e;
            sm += __expf(e - mx);
        }
        #pragma unroll
        for (int off = 32; off; off >>= 1) sm += __shfl_down(sm, off, 64);
        dinv = 1.0f / __shfl(sm, 0, 64);
        for (int k = sub; k < deg; k += NSUB) {
            const int j = csr_src[start + k];
            float e = asrc[(size_t)j * 8 + head] + ad;
            e = e > 0.f ? e : 0.2f * e;
            const float wgt = __expf(e - mx);
            uint4 v = *(const uint4*)&h[(size_t)j * F + head * CH + c0];
            const __half* hv = (const __half*)&v;
            #pragma unroll
            for (int c = 0; c < 8; ++c) acc[c] += wgt * __half2float(hv[c]);
        }
    }

    // merge edge-subsets: comb classes mod TPE preserved by offs >= TPE
    #pragma unroll
    for (int c = 0; c < 8; ++c) {
        #pragma unroll
        for (int off = 32; off >= TPE; off >>= 1) acc[c] += __shfl_down(acc[c], off, 64);
    }
    if (lane < TPE) {
        float* p = &partial[((size_t)i * 8 + head) * CH + c0];
        *(float4*)p = make_float4(acc[0] * dinv, acc[1] * dinv, acc[2] * dinv, acc[3] * dinv);
        *(float4*)(p + 4) = make_float4(acc[4] * dinv, acc[5] * dinv, acc[6] * dinv, acc[7] * dinv);
    }
}

// ---------------------------------------------------------------------------
// Merge heads: out = [relu](mean_h partial + bias); fp16 or fp32 output.
// ---------------------------------------------------------------------------
template <int CH, bool RELU, bool HALF_OUT>
__global__ __launch_bounds__(256) void merge_kernel(const float* __restrict__ partial,
                                                    const float* __restrict__ bias,
                                                    void* __restrict__ out) {
    int flat = blockIdx.x * 256 + threadIdx.x;
    int i = flat / CH;
    int c = flat % CH;
    float s = 0.f;
    #pragma unroll
    for (int h8 = 0; h8 < 8; ++h8) s += partial[((size_t)i * 8 + h8) * CH + c];
    s = s * 0.125f + bias[c];
    if (RELU) s = fmaxf(s, 0.f);
    if (HALF_OUT) ((__half*)out)[flat] = __float2half(s);
    else          ((float*)out)[flat] = s;
}

// ---------------------------------------------------------------------------
// Launch
// ---------------------------------------------------------------------------
extern "C" void kernel_launch(void* const* d_in, const int* in_sizes, int n_in,
                              void* d_out, int out_size, void* d_ws, size_t ws_size,
                              hipStream_t stream) {
    const float* x   = (const float*)d_in[0];
    const int*   ei  = (const int*)d_in[1];
    const float* W1  = (const float*)d_in[2];
    const float* b1  = (const float*)d_in[5];
    const float* W2  = (const float*)d_in[6];
    const float* as1 = (const float*)d_in[3];
    const float* ad1 = (const float*)d_in[4];
    const float* as2 = (const float*)d_in[7];
    const float* ad2 = (const float*)d_in[8];
    const float* b2  = (const float*)d_in[9];

    const int n = N_NODES;
    const int e = E_EDGES;

    // ---- workspace layout (partial region also hosts xh/w1t early on) ----
    char* w = (char*)d_ws;
    float*  partial = (float*)w;                            // 40.96 MB
    __half* xh      = (__half*)w;                           // alias: 10.24 MB
    __half* w1t     = (__half*)(w + 11u * 1024 * 1024);     // alias: +256 KB
    w += (size_t)n * 8 * 64 * 4;
    __half* h_buf = (__half*)w; w += (size_t)n * 512 * 2;   // 20.48 MB
    __half* y1    = (__half*)w; w += (size_t)n * 64 * 2;    // 2.56 MB
    __half* w2t   = (__half*)w; w += 256 * 64 * 2;
    float* asrc   = (float*)w; w += (size_t)n * 8 * 4;
    float* adst   = (float*)w; w += (size_t)n * 8 * 4;
    int* deg       = (int*)w; w += (size_t)n * 4;
    int* row_start = (int*)w; w += (size_t)(n + 1) * 4;
    int* cursor    = (int*)w; w += (size_t)n * 4;
    int* csr_src   = (int*)w; w += (size_t)(e + n) * 4;

    // ---- CSR build (graph identical for both layers) ----
    init_deg_kernel<<<(n + 255) / 256, 256, 0, stream>>>(deg, n);
    count_deg_kernel<<<(e + 255) / 256, 256, 0, stream>>>(ei, e, deg);
    scan_kernel<<<1, 1024, 0, stream>>>(deg, row_start, cursor, n);
    scatter_kernel<<<(e + n + 255) / 256, 256, 0, stream>>>(ei, e, n, cursor, csr_src);

    // ---- casts ----
    cast_x_kernel<<<(n * 256 / 8 + 255) / 256, 256, 0, stream>>>(x, xh, n * 256 / 8);
    cast_wt_kernel<<<512, 256, 0, stream>>>(W1, w1t, 256, 512);
    cast_wt_kernel<<<256, 256, 0, stream>>>(W2, w2t, 64, 256);

    // ---- Layer 1 ----
    gemm_f16_kernel<<<dim3((n + 63) / 64, 8), 256, 0, stream>>>(xh, w1t, h_buf, n, 256, 512);
    logits_kernel<64><<<n / 4, 256, 0, stream>>>(h_buf, as1, ad1, asrc, adst);
    aggregate_kernel<64><<<n * 8, 64, 0, stream>>>(h_buf, asrc, adst, row_start,
                                                   csr_src, partial);   // clobbers xh/w1t (dead)
    merge_kernel<64, true, true><<<n * 64 / 256, 256, 0, stream>>>(partial, b1, y1);

    // ---- Layer 2 ----
    gemm_f16_kernel<<<dim3((n + 63) / 64, 4), 256, 0, stream>>>(y1, w2t, h_buf, n, 64, 256);
    logits_kernel<32><<<n / 4, 256, 0, stream>>>(h_buf, as2, ad2, asrc, adst);
    aggregate_kernel<32><<<n * 8, 64, 0, stream>>>(h_buf, asrc, adst, row_start,
                                                   csr_src, partial);
    merge_kernel<32, false, false><<<n * 32 / 256, 256, 0, stream>>>(partial, b2, (float*)d_out);
}

// Round 6
// 352.235 us; speedup vs baseline: 1.6221x; 1.1319x over previous
//
#include <hip/hip_runtime.h>
#include <hip/hip_fp16.h>

// Problem constants (match reference setup_inputs()).
#define N_NODES 20000
#define E_EDGES 640000
// Layer dims: IN=256, H=8, HF=64, OUT=32

using half8_t = __attribute__((ext_vector_type(8))) _Float16;
using f32x4   = __attribute__((ext_vector_type(4))) float;

// ---------------------------------------------------------------------------
// CSR build: deg init (self-loop counts as 1), count, scan, scatter
// ---------------------------------------------------------------------------
__global__ __launch_bounds__(256) void init_deg_kernel(int* __restrict__ deg, int n) {
    int i = blockIdx.x * 256 + threadIdx.x;
    if (i < n) deg[i] = 1;
}

__global__ __launch_bounds__(256) void count_deg_kernel(const int* __restrict__ ei, int e,
                                                        int* __restrict__ deg) {
    int i = blockIdx.x * 256 + threadIdx.x;
    if (i < e) atomicAdd(&deg[ei[e + i]], 1);  // ei[1][i] = dst
}

__global__ __launch_bounds__(1024) void scan_kernel(const int* __restrict__ deg,
                                                    int* __restrict__ row_start,
                                                    int* __restrict__ cursor, int n) {
    __shared__ int wsum[16];
    __shared__ int carry_s;
    const int t = threadIdx.x;
    const int lane = t & 63;
    const int wv = t >> 6;
    int running = 0;
    for (int base = 0; base < n; base += 1024) {
        int idx = base + t;
        int v = (idx < n) ? deg[idx] : 0;
        int x = v;
        #pragma unroll
        for (int off = 1; off < 64; off <<= 1) {
            int y = __shfl_up(x, off, 64);
            if (lane >= off) x += y;
        }
        if (lane == 63) wsum[wv] = x;
        __syncthreads();
        if (wv == 0 && lane < 16) {
            int w = wsum[lane];
            int xx = w;
            #pragma unroll
            for (int off = 1; off < 16; off <<= 1) {
                int y = __shfl_up(xx, off, 64);
                if (lane >= off) xx += y;
            }
            wsum[lane] = xx - w;
            if (lane == 15) carry_s = xx;
        }
        __syncthreads();
        int excl = running + wsum[wv] + (x - v);
        if (idx < n) { row_start[idx] = excl; cursor[idx] = excl; }
        running += carry_s;
        __syncthreads();
    }
    if (t == 0) row_start[n] = running;
}

__global__ __launch_bounds__(256) void scatter_kernel(const int* __restrict__ ei, int e, int n,
                                                      int* __restrict__ cursor,
                                                      int* __restrict__ csr_src) {
    int i = blockIdx.x * 256 + threadIdx.x;
    if (i >= e + n) return;
    int s, d;
    if (i < e) { s = ei[i]; d = ei[e + i]; }
    else       { s = i - e; d = s; }       // self-loop
    int slot = atomicAdd(&cursor[d], 1);
    csr_src[slot] = s;
}

// ---------------------------------------------------------------------------
// Cast kernels: x -> fp16; W -> fp16 transposed (rows = output col, cols = k)
// ---------------------------------------------------------------------------
__global__ __launch_bounds__(256) void cast_x_kernel(const float* __restrict__ x,
                                                     __half* __restrict__ xh, int total8) {
    int t = blockIdx.x * 256 + threadIdx.x;
    if (t >= total8) return;
    size_t o = (size_t)t * 8;
    float4 a = *(const float4*)&x[o];
    float4 b = *(const float4*)&x[o + 4];
    union { __half h[8]; uint4 u; } pk;
    pk.h[0] = __float2half(a.x); pk.h[1] = __float2half(a.y);
    pk.h[2] = __float2half(a.z); pk.h[3] = __float2half(a.w);
    pk.h[4] = __float2half(b.x); pk.h[5] = __float2half(b.y);
    pk.h[6] = __float2half(b.z); pk.h[7] = __float2half(b.w);
    *(uint4*)&xh[o] = pk.u;
}

// W[K][N] -> Wt[N][K] fp16.  grid.x = N, block = 256 (K <= 256 per call)
__global__ __launch_bounds__(256) void cast_wt_kernel(const float* __restrict__ W,
                                                      __half* __restrict__ Wt, int K, int N) {
    int nrow = blockIdx.x;
    int k = threadIdx.x;
    if (k < K) Wt[(size_t)nrow * K + k] = __float2half(W[(size_t)k * N + nrow]);
}

// ---------------------------------------------------------------------------
// fp16 MFMA GEMM: C[M,N] = A[M,K] @ B[K,N], B given TRANSPOSED as Bt[N][K].
// fp16 in, fp16 out, fp32 accumulate. K % 32 == 0, N % 64 == 0.
// ---------------------------------------------------------------------------
__global__ __launch_bounds__(256) void gemm_f16_kernel(const __half* __restrict__ A,
                                                       const __half* __restrict__ Bt,
                                                       __half* __restrict__ C,
                                                       int M, int K, int N) {
    constexpr int LDT = 40;  // LDS row stride in halves (32 + 8 pad)
    __shared__ __align__(16) _Float16 As[64 * LDT];
    __shared__ __align__(16) _Float16 Bs[64 * LDT];
    const int tid = threadIdx.x;
    const int bm = blockIdx.x * 64;
    const int bn = blockIdx.y * 64;
    const int w = tid >> 6;
    const int lane = tid & 63;
    const int l16 = lane & 15;
    const int quad = lane >> 4;
    const int srow = tid >> 2;        // staging row 0..63
    const int skg = tid & 3;          // staging k-group (8 halves each)

    f32x4 acc[4];
    #pragma unroll
    for (int c = 0; c < 4; ++c) acc[c] = (f32x4){0.f, 0.f, 0.f, 0.f};

    for (int k0 = 0; k0 < K; k0 += 32) {
        uint4 av = make_uint4(0, 0, 0, 0);
        if (bm + srow < M) av = *(const uint4*)&A[(size_t)(bm + srow) * K + k0 + skg * 8];
        uint4 bv = *(const uint4*)&Bt[(size_t)(bn + srow) * K + k0 + skg * 8];
        *(uint4*)&As[srow * LDT + skg * 8] = av;
        *(uint4*)&Bs[srow * LDT + skg * 8] = bv;
        __syncthreads();

        half8_t af = *(const half8_t*)&As[(w * 16 + l16) * LDT + quad * 8];
        #pragma unroll
        for (int c = 0; c < 4; ++c) {
            half8_t bf = *(const half8_t*)&Bs[(c * 16 + l16) * LDT + quad * 8];
            acc[c] = __builtin_amdgcn_mfma_f32_16x16x32_f16(af, bf, acc[c], 0, 0, 0);
        }
        __syncthreads();
    }

    #pragma unroll
    for (int c = 0; c < 4; ++c) {
        #pragma unroll
        for (int r = 0; r < 4; ++r) {
            int row = bm + w * 16 + quad * 4 + r;
            if (row < M)
                C[(size_t)row * N + bn + c * 16 + l16] = __float2half(acc[c][r]);
        }
    }
}

// ---------------------------------------------------------------------------
// Per-node attention logits (fp16 h). One wave per node, 4 nodes per block.
// ---------------------------------------------------------------------------
template <int CH>
__global__ __launch_bounds__(256) void logits_kernel(const __half* __restrict__ h,
                                                     const float* __restrict__ att_src,
                                                     const float* __restrict__ att_dst,
                                                     float* __restrict__ asrc,
                                                     float* __restrict__ adst) {
    constexpr int F = 8 * CH;
    constexpr int J = F / 64;        // halves per lane: 8 (CH=64) or 4 (CH=32)
    const int tid = threadIdx.x;
    const int i = blockIdx.x * 4 + (tid >> 6);
    const int lane = tid & 63;
    const size_t hoff = (size_t)i * F + lane * J;
    float ps = 0.f, pd = 0.f;
    if (J == 8) {
        uint4 hv = *(const uint4*)&h[hoff];
        const __half* hp = (const __half*)&hv;
        #pragma unroll
        for (int j = 0; j < 8; ++j) {
            float v = __half2float(hp[j]);
            ps += v * att_src[lane * 8 + j];
            pd += v * att_dst[lane * 8 + j];
        }
    } else {
        uint2 hv = *(const uint2*)&h[hoff];
        const __half* hp = (const __half*)&hv;
        #pragma unroll
        for (int j = 0; j < 4; ++j) {
            float v = __half2float(hp[j]);
            ps += v * att_src[lane * 4 + j];
            pd += v * att_dst[lane * 4 + j];
        }
    }
    #pragma unroll
    for (int off = 4; off; off >>= 1) {
        ps += __shfl_down(ps, off, 64);
        pd += __shfl_down(pd, off, 64);
    }
    if ((lane & 7) == 0) {
        asrc[(size_t)i * 8 + (lane >> 3)] = ps;
        adst[(size_t)i * 8 + (lane >> 3)] = pd;
    }
}

// ---------------------------------------------------------------------------
// Aggregation v6: one WAVE per (dst, head), blockIdx = dst*8 + head (XCD
// locality: head h -> XCD h, per-XCD h-slice 2.56 MB -> L2-resident).
// v6 changes vs v5: (1) phase-3 unrolled with batched uint4 staging (UNR
// loads in flight), (2) final cross-subset reduction through LDS instead of
// 24-shfl chains, (3) unified epilogue for fast/fallback paths.
// ---------------------------------------------------------------------------
template <int CH>
__global__ __launch_bounds__(64) void aggregate_kernel(const __half* __restrict__ h,
                                                       const float* __restrict__ asrc,
                                                       const float* __restrict__ adst,
                                                       const int* __restrict__ row_start,
                                                       const int* __restrict__ csr_src,
                                                       float* __restrict__ partial) {
    constexpr int F = 8 * CH;
    constexpr int TPE = CH / 8;          // lanes per edge: 8 (CH=64) / 4 (CH=32)
    constexpr int NSUB = 64 / TPE;       // edges in flight: 8 / 16
    constexpr int UNR = (CH == 64) ? 4 : 2;  // unrolled edge-groups per step
    constexpr int MAXD = 128;
    __shared__ int   s_src[MAXD];
    __shared__ float s_e[MAXD];
    __shared__ float s_part[NSUB * CH];  // 512 floats
    const int b = blockIdx.x;
    const int head = b & 7;
    const int i = b >> 3;
    const int lane = threadIdx.x;
    const int start = row_start[i];
    const int deg = row_start[i + 1] - start;
    const float ad = adst[(size_t)i * 8 + head];

    const int sub = lane / TPE;
    const int c0 = (lane % TPE) * 8;
    const __half* __restrict__ hb = h + head * CH + c0;
    float acc[8];
    #pragma unroll
    for (int c = 0; c < 8; ++c) acc[c] = 0.f;
    float dinv;

    if (deg <= MAXD) {
        // phase 1: stage src + e, track max
        float mx = -1e30f;
        for (int k = lane; k < deg; k += 64) {
            int j = csr_src[start + k];
            s_src[k] = j;
            float e = asrc[(size_t)j * 8 + head] + ad;
            e = e > 0.f ? e : 0.2f * e;
            s_e[k] = e;
            mx = fmaxf(mx, e);
        }
        #pragma unroll
        for (int off = 32; off; off >>= 1) mx = fmaxf(mx, __shfl_down(mx, off, 64));
        mx = __shfl(mx, 0, 64);
        __syncthreads();
        // phase 2: exp in place + sum
        float sm = 0.f;
        for (int k = lane; k < deg; k += 64) {
            float ex = __expf(s_e[k] - mx);
            s_e[k] = ex;
            sm += ex;
        }
        #pragma unroll
        for (int off = 32; off; off >>= 1) sm += __shfl_down(sm, off, 64);
        dinv = 1.0f / __shfl(sm, 0, 64);
        __syncthreads();
        // phase 3: gather head-slice, UNR independent 16B loads in flight
        int k = sub;
        for (; k + (UNR - 1) * NSUB < deg; k += UNR * NSUB) {
            int   jj[UNR];
            float ww[UNR];
            uint4 vv[UNR];
            #pragma unroll
            for (int u = 0; u < UNR; ++u) {
                jj[u] = s_src[k + u * NSUB];
                ww[u] = s_e[k + u * NSUB];
            }
            #pragma unroll
            for (int u = 0; u < UNR; ++u)
                vv[u] = *(const uint4*)&hb[(size_t)jj[u] * F];
            #pragma unroll
            for (int u = 0; u < UNR; ++u) {
                const __half* hv = (const __half*)&vv[u];
                #pragma unroll
                for (int c = 0; c < 8; ++c) acc[c] += ww[u] * __half2float(hv[c]);
            }
        }
        for (; k < deg; k += NSUB) {
            const float wgt = s_e[k];
            uint4 v = *(const uint4*)&hb[(size_t)s_src[k] * F];
            const __half* hv = (const __half*)&v;
            #pragma unroll
            for (int c = 0; c < 8; ++c) acc[c] += wgt * __half2float(hv[c]);
        }
    } else {
        // fallback (deg > MAXD): streaming recompute, no LDS edge cache
        float mx = -1e30f;
        for (int k = lane; k < deg; k += 64) {
            int j = csr_src[start + k];
            float e = asrc[(size_t)j * 8 + head] + ad;
            e = e > 0.f ? e : 0.2f * e;
            mx = fmaxf(mx, e);
        }
        #pragma unroll
        for (int off = 32; off; off >>= 1) mx = fmaxf(mx, __shfl_down(mx, off, 64));
        mx = __shfl(mx, 0, 64);
        float sm = 0.f;
        for (int k = lane; k < deg; k += 64) {
            int j = csr_src[start + k];
            float e = asrc[(size_t)j * 8 + head] + ad;
            e = e > 0.f ? e : 0.2f * e;
            sm += __expf(e - mx);
        }
        #pragma unroll
        for (int off = 32; off; off >>= 1) sm += __shfl_down(sm, off, 64);
        dinv = 1.0f / __shfl(sm, 0, 64);
        for (int k = sub; k < deg; k += NSUB) {
            const int j = csr_src[start + k];
            float e = asrc[(size_t)j * 8 + head] + ad;
            e = e > 0.f ? e : 0.2f * e;
            const float wgt = __expf(e - mx);
            uint4 v = *(const uint4*)&hb[(size_t)j * F];
            const __half* hv = (const __half*)&v;
            #pragma unroll
            for (int c = 0; c < 8; ++c) acc[c] += wgt * __half2float(hv[c]);
        }
        __syncthreads();  // match fast path's barrier count before s_part use
    }

    // ---- epilogue: reduce across edge-subsets via LDS ----
    // lane writes acc[8] at flat = sub*CH + c0 == lane*8
    *(float4*)&s_part[lane * 8] = make_float4(acc[0], acc[1], acc[2], acc[3]);
    *(float4*)&s_part[lane * 8 + 4] = make_float4(acc[4], acc[5], acc[6], acc[7]);
    __syncthreads();

    if (CH == 64) {
        // lane c sums subs 0..7 for channel c
        float v = 0.f;
        #pragma unroll
        for (int s = 0; s < 8; ++s) v += s_part[s * CH + lane];
        partial[((size_t)i * 8 + head) * CH + lane] = v * dinv;
    } else {
        // 16 subs: lane ℓ sums 8 subs for channel ℓ%32, then pair-merge
        const int c = lane & 31;
        const int sh = lane >> 5;       // 0 or 1
        float v = 0.f;
        #pragma unroll
        for (int s = 0; s < 8; ++s) v += s_part[(sh * 8 + s) * CH + c];
        v += __shfl_down(v, 32, 64);
        if (lane < 32)
            partial[((size_t)i * 8 + head) * CH + c] = v * dinv;
    }
}

// ---------------------------------------------------------------------------
// Merge heads: out = [relu](mean_h partial + bias); fp16 or fp32 output.
// ---------------------------------------------------------------------------
template <int CH, bool RELU, bool HALF_OUT>
__global__ __launch_bounds__(256) void merge_kernel(const float* __restrict__ partial,
                                                    const float* __restrict__ bias,
                                                    void* __restrict__ out) {
    int flat = blockIdx.x * 256 + threadIdx.x;
    int i = flat / CH;
    int c = flat % CH;
    float s = 0.f;
    #pragma unroll
    for (int h8 = 0; h8 < 8; ++h8) s += partial[((size_t)i * 8 + h8) * CH + c];
    s = s * 0.125f + bias[c];
    if (RELU) s = fmaxf(s, 0.f);
    if (HALF_OUT) ((__half*)out)[flat] = __float2half(s);
    else          ((float*)out)[flat] = s;
}

// ---------------------------------------------------------------------------
// Launch
// ---------------------------------------------------------------------------
extern "C" void kernel_launch(void* const* d_in, const int* in_sizes, int n_in,
                              void* d_out, int out_size, void* d_ws, size_t ws_size,
                              hipStream_t stream) {
    const float* x   = (const float*)d_in[0];
    const int*   ei  = (const int*)d_in[1];
    const float* W1  = (const float*)d_in[2];
    const float* as1 = (const float*)d_in[3];
    const float* ad1 = (const float*)d_in[4];
    const float* b1  = (const float*)d_in[5];
    const float* W2  = (const float*)d_in[6];
    const float* as2 = (const float*)d_in[7];
    const float* ad2 = (const float*)d_in[8];
    const float* b2  = (const float*)d_in[9];

    const int n = N_NODES;
    const int e = E_EDGES;

    // ---- workspace layout (partial region also hosts xh/w1t early on) ----
    char* w = (char*)d_ws;
    float*  partial = (float*)w;                            // 40.96 MB
    __half* xh      = (__half*)w;                           // alias: 10.24 MB
    __half* w1t     = (__half*)(w + 11u * 1024 * 1024);     // alias: +256 KB
    w += (size_t)n * 8 * 64 * 4;
    __half* h_buf = (__half*)w; w += (size_t)n * 512 * 2;   // 20.48 MB
    __half* y1    = (__half*)w; w += (size_t)n * 64 * 2;    // 2.56 MB
    __half* w2t   = (__half*)w; w += 256 * 64 * 2;
    float* asrc   = (float*)w; w += (size_t)n * 8 * 4;
    float* adst   = (float*)w; w += (size_t)n * 8 * 4;
    int* deg       = (int*)w; w += (size_t)n * 4;
    int* row_start = (int*)w; w += (size_t)(n + 1) * 4;
    int* cursor    = (int*)w; w += (size_t)n * 4;
    int* csr_src   = (int*)w; w += (size_t)(e + n) * 4;

    // ---- CSR build (graph identical for both layers) ----
    init_deg_kernel<<<(n + 255) / 256, 256, 0, stream>>>(deg, n);
    count_deg_kernel<<<(e + 255) / 256, 256, 0, stream>>>(ei, e, deg);
    scan_kernel<<<1, 1024, 0, stream>>>(deg, row_start, cursor, n);
    scatter_kernel<<<(e + n + 255) / 256, 256, 0, stream>>>(ei, e, n, cursor, csr_src);

    // ---- casts ----
    cast_x_kernel<<<(n * 256 / 8 + 255) / 256, 256, 0, stream>>>(x, xh, n * 256 / 8);
    cast_wt_kernel<<<512, 256, 0, stream>>>(W1, w1t, 256, 512);
    cast_wt_kernel<<<256, 256, 0, stream>>>(W2, w2t, 64, 256);

    // ---- Layer 1 ----
    gemm_f16_kernel<<<dim3((n + 63) / 64, 8), 256, 0, stream>>>(xh, w1t, h_buf, n, 256, 512);
    logits_kernel<64><<<n / 4, 256, 0, stream>>>(h_buf, as1, ad1, asrc, adst);
    aggregate_kernel<64><<<n * 8, 64, 0, stream>>>(h_buf, asrc, adst, row_start,
                                                   csr_src, partial);   // clobbers xh/w1t (dead)
    merge_kernel<64, true, true><<<n * 64 / 256, 256, 0, stream>>>(partial, b1, y1);

    // ---- Layer 2 ----
    gemm_f16_kernel<<<dim3((n + 63) / 64, 4), 256, 0, stream>>>(y1, w2t, h_buf, n, 64, 256);
    logits_kernel<32><<<n / 4, 256, 0, stream>>>(h_buf, as2, ad2, asrc, adst);
    aggregate_kernel<32><<<n * 8, 64, 0, stream>>>(h_buf, asrc, adst, row_start,
                                                   csr_src, partial);
    merge_kernel<32, false, false><<<n * 32 / 256, 256, 0, stream>>>(partial, b2, (float*)d_out);
}

// Round 7
// 343.891 us; speedup vs baseline: 1.6615x; 1.0243x over previous
//
#include <hip/hip_runtime.h>
#include <hip/hip_fp16.h>

// Problem constants (match reference setup_inputs()).
#define N_NODES 20000
#define E_EDGES 640000
// Layer dims: IN=256, H=8, HF=64, OUT=32

using half8_t = __attribute__((ext_vector_type(8))) _Float16;
using f32x4   = __attribute__((ext_vector_type(4))) float;

// ---------------------------------------------------------------------------
// CSR build: deg init (self-loop counts as 1), count, scan, scatter
// ---------------------------------------------------------------------------
__global__ __launch_bounds__(256) void init_deg_kernel(int* __restrict__ deg, int n) {
    int i = blockIdx.x * 256 + threadIdx.x;
    if (i < n) deg[i] = 1;
}

__global__ __launch_bounds__(256) void count_deg_kernel(const int* __restrict__ ei, int e,
                                                        int* __restrict__ deg) {
    int i = blockIdx.x * 256 + threadIdx.x;
    if (i < e) atomicAdd(&deg[ei[e + i]], 1);  // ei[1][i] = dst
}

__global__ __launch_bounds__(1024) void scan_kernel(const int* __restrict__ deg,
                                                    int* __restrict__ row_start,
                                                    int* __restrict__ cursor, int n) {
    __shared__ int wsum[16];
    __shared__ int carry_s;
    const int t = threadIdx.x;
    const int lane = t & 63;
    const int wv = t >> 6;
    int running = 0;
    for (int base = 0; base < n; base += 1024) {
        int idx = base + t;
        int v = (idx < n) ? deg[idx] : 0;
        int x = v;
        #pragma unroll
        for (int off = 1; off < 64; off <<= 1) {
            int y = __shfl_up(x, off, 64);
            if (lane >= off) x += y;
        }
        if (lane == 63) wsum[wv] = x;
        __syncthreads();
        if (wv == 0 && lane < 16) {
            int w = wsum[lane];
            int xx = w;
            #pragma unroll
            for (int off = 1; off < 16; off <<= 1) {
                int y = __shfl_up(xx, off, 64);
                if (lane >= off) xx += y;
            }
            wsum[lane] = xx - w;
            if (lane == 15) carry_s = xx;
        }
        __syncthreads();
        int excl = running + wsum[wv] + (x - v);
        if (idx < n) { row_start[idx] = excl; cursor[idx] = excl; }
        running += carry_s;
        __syncthreads();
    }
    if (t == 0) row_start[n] = running;
}

__global__ __launch_bounds__(256) void scatter_kernel(const int* __restrict__ ei, int e, int n,
                                                      int* __restrict__ cursor,
                                                      int* __restrict__ csr_src) {
    int i = blockIdx.x * 256 + threadIdx.x;
    if (i >= e + n) return;
    int s, d;
    if (i < e) { s = ei[i]; d = ei[e + i]; }
    else       { s = i - e; d = s; }       // self-loop
    int slot = atomicAdd(&cursor[d], 1);
    csr_src[slot] = s;
}

// ---------------------------------------------------------------------------
// Cast kernels: x -> fp16; W -> fp16 transposed (rows = output col, cols = k)
// ---------------------------------------------------------------------------
__global__ __launch_bounds__(256) void cast_x_kernel(const float* __restrict__ x,
                                                     __half* __restrict__ xh, int total8) {
    int t = blockIdx.x * 256 + threadIdx.x;
    if (t >= total8) return;
    size_t o = (size_t)t * 8;
    float4 a = *(const float4*)&x[o];
    float4 b = *(const float4*)&x[o + 4];
    union { __half h[8]; uint4 u; } pk;
    pk.h[0] = __float2half(a.x); pk.h[1] = __float2half(a.y);
    pk.h[2] = __float2half(a.z); pk.h[3] = __float2half(a.w);
    pk.h[4] = __float2half(b.x); pk.h[5] = __float2half(b.y);
    pk.h[6] = __float2half(b.z); pk.h[7] = __float2half(b.w);
    *(uint4*)&xh[o] = pk.u;
}

// W[K][N] -> Wt[N][K] fp16.  grid.x = N, block = 256 (K <= 256 per call)
__global__ __launch_bounds__(256) void cast_wt_kernel(const float* __restrict__ W,
                                                      __half* __restrict__ Wt, int K, int N) {
    int nrow = blockIdx.x;
    int k = threadIdx.x;
    if (k < K) Wt[(size_t)nrow * K + k] = __float2half(W[(size_t)k * N + nrow]);
}

// ---------------------------------------------------------------------------
// fp16 MFMA GEMM: C[M,N] = A[M,K] @ B[K,N], B given TRANSPOSED as Bt[N][K].
// fp16 in, fp16 out, fp32 accumulate. K % 32 == 0, N % 64 == 0.
// ---------------------------------------------------------------------------
__global__ __launch_bounds__(256) void gemm_f16_kernel(const __half* __restrict__ A,
                                                       const __half* __restrict__ Bt,
                                                       __half* __restrict__ C,
                                                       int M, int K, int N) {
    constexpr int LDT = 40;  // LDS row stride in halves (32 + 8 pad)
    __shared__ __align__(16) _Float16 As[64 * LDT];
    __shared__ __align__(16) _Float16 Bs[64 * LDT];
    const int tid = threadIdx.x;
    const int bm = blockIdx.x * 64;
    const int bn = blockIdx.y * 64;
    const int w = tid >> 6;
    const int lane = tid & 63;
    const int l16 = lane & 15;
    const int quad = lane >> 4;
    const int srow = tid >> 2;        // staging row 0..63
    const int skg = tid & 3;          // staging k-group (8 halves each)

    f32x4 acc[4];
    #pragma unroll
    for (int c = 0; c < 4; ++c) acc[c] = (f32x4){0.f, 0.f, 0.f, 0.f};

    for (int k0 = 0; k0 < K; k0 += 32) {
        uint4 av = make_uint4(0, 0, 0, 0);
        if (bm + srow < M) av = *(const uint4*)&A[(size_t)(bm + srow) * K + k0 + skg * 8];
        uint4 bv = *(const uint4*)&Bt[(size_t)(bn + srow) * K + k0 + skg * 8];
        *(uint4*)&As[srow * LDT + skg * 8] = av;
        *(uint4*)&Bs[srow * LDT + skg * 8] = bv;
        __syncthreads();

        half8_t af = *(const half8_t*)&As[(w * 16 + l16) * LDT + quad * 8];
        #pragma unroll
        for (int c = 0; c < 4; ++c) {
            half8_t bf = *(const half8_t*)&Bs[(c * 16 + l16) * LDT + quad * 8];
            acc[c] = __builtin_amdgcn_mfma_f32_16x16x32_f16(af, bf, acc[c], 0, 0, 0);
        }
        __syncthreads();
    }

    #pragma unroll
    for (int c = 0; c < 4; ++c) {
        #pragma unroll
        for (int r = 0; r < 4; ++r) {
            int row = bm + w * 16 + quad * 4 + r;
            if (row < M)
                C[(size_t)row * N + bn + c * 16 + l16] = __float2half(acc[c][r]);
        }
    }
}

// ---------------------------------------------------------------------------
// Per-node attention logits (fp16 h). One wave per node, 4 nodes per block.
// ---------------------------------------------------------------------------
template <int CH>
__global__ __launch_bounds__(256) void logits_kernel(const __half* __restrict__ h,
                                                     const float* __restrict__ att_src,
                                                     const float* __restrict__ att_dst,
                                                     float* __restrict__ asrc,
                                                     float* __restrict__ adst) {
    constexpr int F = 8 * CH;
    constexpr int J = F / 64;        // halves per lane: 8 (CH=64) or 4 (CH=32)
    const int tid = threadIdx.x;
    const int i = blockIdx.x * 4 + (tid >> 6);
    const int lane = tid & 63;
    const size_t hoff = (size_t)i * F + lane * J;
    float ps = 0.f, pd = 0.f;
    if (J == 8) {
        uint4 hv = *(const uint4*)&h[hoff];
        const __half* hp = (const __half*)&hv;
        #pragma unroll
        for (int j = 0; j < 8; ++j) {
            float v = __half2float(hp[j]);
            ps += v * att_src[lane * 8 + j];
            pd += v * att_dst[lane * 8 + j];
        }
    } else {
        uint2 hv = *(const uint2*)&h[hoff];
        const __half* hp = (const __half*)&hv;
        #pragma unroll
        for (int j = 0; j < 4; ++j) {
            float v = __half2float(hp[j]);
            ps += v * att_src[lane * 4 + j];
            pd += v * att_dst[lane * 4 + j];
        }
    }
    #pragma unroll
    for (int off = 4; off; off >>= 1) {
        ps += __shfl_down(ps, off, 64);
        pd += __shfl_down(pd, off, 64);
    }
    if ((lane & 7) == 0) {
        asrc[(size_t)i * 8 + (lane >> 3)] = ps;
        adst[(size_t)i * 8 + (lane >> 3)] = pd;
    }
}

// ---------------------------------------------------------------------------
// Aggregation v7: one WAVE per (dst, head), blockIdx = dst*8 + head (XCD
// locality: head h -> XCD h, per-XCD h-slice 2.56 MB -> L2-resident).
// v7 vs v6: (1) single-pass softmax WITHOUT max-subtract (fp32 exp is
// range-safe; alpha is scale-invariant) -> 1 barrier, half the shfls;
// (2) LDS stores pre-scaled byte offsets (kills per-lane v_mul in phase 3);
// (3) fp16 partial output (halves partial traffic).
// ---------------------------------------------------------------------------
template <int CH>
__global__ __launch_bounds__(64) void aggregate_kernel(const __half* __restrict__ h,
                                                       const float* __restrict__ asrc,
                                                       const float* __restrict__ adst,
                                                       const int* __restrict__ row_start,
                                                       const int* __restrict__ csr_src,
                                                       __half* __restrict__ partial) {
    constexpr int F = 8 * CH;
    constexpr int TPE = CH / 8;          // lanes per edge: 8 (CH=64) / 4 (CH=32)
    constexpr int NSUB = 64 / TPE;       // edges in flight: 8 / 16
    constexpr int UNR = (CH == 64) ? 4 : 2;  // unrolled edge-groups per step
    constexpr int MAXD = 128;
    __shared__ int   s_off[MAXD];        // pre-scaled byte offsets j*F*2
    __shared__ float s_e[MAXD];          // exp(e) (unnormalized)
    __shared__ float s_part[NSUB * CH];  // 512 floats
    const int b = blockIdx.x;
    const int head = b & 7;
    const int i = b >> 3;
    const int lane = threadIdx.x;
    const int start = row_start[i];
    const int deg = row_start[i + 1] - start;
    const float ad = adst[i * 8 + head];

    const int sub = lane / TPE;
    const int c0 = (lane % TPE) * 8;
    const char* __restrict__ hb = (const char*)h + (head * CH + c0) * 2;
    float acc[8];
    #pragma unroll
    for (int c = 0; c < 8; ++c) acc[c] = 0.f;
    float dinv;

    if (deg <= MAXD) {
        // ---- phase 1+2 fused: e -> exp -> LDS, register partial sum ----
        float lsum = 0.f;
        for (int k = lane; k < deg; k += 64) {
            int j = csr_src[start + k];
            float e = asrc[j * 8 + head] + ad;
            e = e > 0.f ? e : 0.2f * e;
            float ex = __expf(e);       // fp32 exp: range-safe, no max needed
            s_off[k] = j * (F * 2);
            s_e[k] = ex;
            lsum += ex;
        }
        #pragma unroll
        for (int off = 32; off; off >>= 1) lsum += __shfl_down(lsum, off, 64);
        dinv = 1.0f / __shfl(lsum, 0, 64);
        __syncthreads();

        // ---- phase 3: gather head-slice, UNR independent 16B loads ----
        int k = sub;
        for (; k + (UNR - 1) * NSUB < deg; k += UNR * NSUB) {
            int   oo[UNR];
            float ww[UNR];
            uint4 vv[UNR];
            #pragma unroll
            for (int u = 0; u < UNR; ++u) {
                oo[u] = s_off[k + u * NSUB];
                ww[u] = s_e[k + u * NSUB];
            }
            #pragma unroll
            for (int u = 0; u < UNR; ++u)
                vv[u] = *(const uint4*)(hb + oo[u]);
            #pragma unroll
            for (int u = 0; u < UNR; ++u) {
                const __half* hv = (const __half*)&vv[u];
                #pragma unroll
                for (int c = 0; c < 8; ++c) acc[c] += ww[u] * __half2float(hv[c]);
            }
        }
        for (; k < deg; k += NSUB) {
            const float wgt = s_e[k];
            uint4 v = *(const uint4*)(hb + s_off[k]);
            const __half* hv = (const __half*)&v;
            #pragma unroll
            for (int c = 0; c < 8; ++c) acc[c] += wgt * __half2float(hv[c]);
        }
    } else {
        // ---- fallback (deg > MAXD): two-pass streaming, no LDS edge cache ----
        float lsum = 0.f;
        for (int k = lane; k < deg; k += 64) {
            int j = csr_src[start + k];
            float e = asrc[j * 8 + head] + ad;
            e = e > 0.f ? e : 0.2f * e;
            lsum += __expf(e);
        }
        #pragma unroll
        for (int off = 32; off; off >>= 1) lsum += __shfl_down(lsum, off, 64);
        dinv = 1.0f / __shfl(lsum, 0, 64);
        for (int k = sub; k < deg; k += NSUB) {
            const int j = csr_src[start + k];
            float e = asrc[j * 8 + head] + ad;
            e = e > 0.f ? e : 0.2f * e;
            const float wgt = __expf(e);
            uint4 v = *(const uint4*)(hb + (size_t)j * (F * 2));
            const __half* hv = (const __half*)&v;
            #pragma unroll
            for (int c = 0; c < 8; ++c) acc[c] += wgt * __half2float(hv[c]);
        }
    }

    // ---- epilogue: reduce across edge-subsets via LDS, fp16 store ----
    // lane writes acc[8] at flat = sub*CH + c0 == lane*8
    *(float4*)&s_part[lane * 8] = make_float4(acc[0], acc[1], acc[2], acc[3]);
    *(float4*)&s_part[lane * 8 + 4] = make_float4(acc[4], acc[5], acc[6], acc[7]);
    __syncthreads();

    if (CH == 64) {
        float v = 0.f;
        #pragma unroll
        for (int s = 0; s < 8; ++s) v += s_part[s * CH + lane];
        partial[((size_t)i * 8 + head) * CH + lane] = __float2half(v * dinv);
    } else {
        const int c = lane & 31;
        const int sh = lane >> 5;       // 0 or 1
        float v = 0.f;
        #pragma unroll
        for (int s = 0; s < 8; ++s) v += s_part[(sh * 8 + s) * CH + c];
        v += __shfl_down(v, 32, 64);
        if (lane < 32)
            partial[((size_t)i * 8 + head) * CH + c] = __float2half(v * dinv);
    }
}

// ---------------------------------------------------------------------------
// Merge heads: out = [relu](mean_h partial + bias); fp16 or fp32 output.
// ---------------------------------------------------------------------------
template <int CH, bool RELU, bool HALF_OUT>
__global__ __launch_bounds__(256) void merge_kernel(const __half* __restrict__ partial,
                                                    const float* __restrict__ bias,
                                                    void* __restrict__ out) {
    int flat = blockIdx.x * 256 + threadIdx.x;
    int i = flat / CH;
    int c = flat % CH;
    float s = 0.f;
    #pragma unroll
    for (int h8 = 0; h8 < 8; ++h8)
        s += __half2float(partial[((size_t)i * 8 + h8) * CH + c]);
    s = s * 0.125f + bias[c];
    if (RELU) s = fmaxf(s, 0.f);
    if (HALF_OUT) ((__half*)out)[flat] = __float2half(s);
    else          ((float*)out)[flat] = s;
}

// ---------------------------------------------------------------------------
// Launch
// ---------------------------------------------------------------------------
extern "C" void kernel_launch(void* const* d_in, const int* in_sizes, int n_in,
                              void* d_out, int out_size, void* d_ws, size_t ws_size,
                              hipStream_t stream) {
    const float* x   = (const float*)d_in[0];
    const int*   ei  = (const int*)d_in[1];
    const float* W1  = (const float*)d_in[2];
    const float* as1 = (const float*)d_in[3];
    const float* ad1 = (const float*)d_in[4];
    const float* b1  = (const float*)d_in[5];
    const float* W2  = (const float*)d_in[6];
    const float* as2 = (const float*)d_in[7];
    const float* ad2 = (const float*)d_in[8];
    const float* b2  = (const float*)d_in[9];

    const int n = N_NODES;
    const int e = E_EDGES;

    // ---- workspace layout (partial region also hosts xh/w1t early on) ----
    char* w = (char*)d_ws;
    __half* partial = (__half*)w;                           // 20.48 MB
    __half* xh      = (__half*)w;                           // alias: 10.24 MB
    __half* w1t     = (__half*)(w + 11u * 1024 * 1024);     // alias: +256 KB
    w += (size_t)n * 8 * 64 * 2;
    __half* h_buf = (__half*)w; w += (size_t)n * 512 * 2;   // 20.48 MB
    __half* y1    = (__half*)w; w += (size_t)n * 64 * 2;    // 2.56 MB
    __half* w2t   = (__half*)w; w += 256 * 64 * 2;
    float* asrc   = (float*)w; w += (size_t)n * 8 * 4;
    float* adst   = (float*)w; w += (size_t)n * 8 * 4;
    int* deg       = (int*)w; w += (size_t)n * 4;
    int* row_start = (int*)w; w += (size_t)(n + 1) * 4;
    int* cursor    = (int*)w; w += (size_t)n * 4;
    int* csr_src   = (int*)w; w += (size_t)(e + n) * 4;

    // ---- CSR build (graph identical for both layers) ----
    init_deg_kernel<<<(n + 255) / 256, 256, 0, stream>>>(deg, n);
    count_deg_kernel<<<(e + 255) / 256, 256, 0, stream>>>(ei, e, deg);
    scan_kernel<<<1, 1024, 0, stream>>>(deg, row_start, cursor, n);
    scatter_kernel<<<(e + n + 255) / 256, 256, 0, stream>>>(ei, e, n, cursor, csr_src);

    // ---- casts ----
    cast_x_kernel<<<(n * 256 / 8 + 255) / 256, 256, 0, stream>>>(x, xh, n * 256 / 8);
    cast_wt_kernel<<<512, 256, 0, stream>>>(W1, w1t, 256, 512);
    cast_wt_kernel<<<256, 256, 0, stream>>>(W2, w2t, 64, 256);

    // ---- Layer 1 ----
    gemm_f16_kernel<<<dim3((n + 63) / 64, 8), 256, 0, stream>>>(xh, w1t, h_buf, n, 256, 512);
    logits_kernel<64><<<n / 4, 256, 0, stream>>>(h_buf, as1, ad1, asrc, adst);
    aggregate_kernel<64><<<n * 8, 64, 0, stream>>>(h_buf, asrc, adst, row_start,
                                                   csr_src, partial);   // clobbers xh/w1t (dead)
    merge_kernel<64, true, true><<<n * 64 / 256, 256, 0, stream>>>(partial, b1, y1);

    // ---- Layer 2 ----
    gemm_f16_kernel<<<dim3((n + 63) / 64, 4), 256, 0, stream>>>(y1, w2t, h_buf, n, 64, 256);
    logits_kernel<32><<<n / 4, 256, 0, stream>>>(h_buf, as2, ad2, asrc, adst);
    aggregate_kernel<32><<<n * 8, 64, 0, stream>>>(h_buf, asrc, adst, row_start,
                                                   csr_src, partial);
    merge_kernel<32, false, false><<<n * 32 / 256, 256, 0, stream>>>(partial, b2, (float*)d_out);
}

// Round 8
// 339.435 us; speedup vs baseline: 1.6833x; 1.0131x over previous
//
#include <hip/hip_runtime.h>
#include <hip/hip_fp16.h>

// Problem constants (match reference setup_inputs()).
#define N_NODES 20000
#define E_EDGES 640000
// Layer dims: IN=256, H=8, HF=64, OUT=32

using half8_t = __attribute__((ext_vector_type(8))) _Float16;
using f32x4   = __attribute__((ext_vector_type(4))) float;

// ---------------------------------------------------------------------------
// CSR build: deg init (self-loop counts as 1), count, scan, scatter
// ---------------------------------------------------------------------------
__global__ __launch_bounds__(256) void init_deg_kernel(int* __restrict__ deg, int n) {
    int i = blockIdx.x * 256 + threadIdx.x;
    if (i < n) deg[i] = 1;
}

__global__ __launch_bounds__(256) void count_deg_kernel(const int* __restrict__ ei, int e,
                                                        int* __restrict__ deg) {
    int i = blockIdx.x * 256 + threadIdx.x;
    if (i < e) atomicAdd(&deg[ei[e + i]], 1);  // ei[1][i] = dst
}

// v2 scan: 1024 threads, each owns 20 contiguous elems (covers 20480 >= n).
// Per-thread sequential prefix, one wave-scan of thread totals, one LDS pass.
__global__ __launch_bounds__(1024) void scan_kernel(const int* __restrict__ deg,
                                                    int* __restrict__ row_start,
                                                    int* __restrict__ cursor,
                                                    int n, int total) {
    constexpr int PT = 20;
    __shared__ int wtot[16];
    const int t = threadIdx.x;
    const int lane = t & 63;
    const int wv = t >> 6;
    const int base = t * PT;
    int loc[PT];
    int s = 0;
    #pragma unroll
    for (int i = 0; i < PT; ++i) {
        int idx = base + i;
        int v = (idx < n) ? deg[idx] : 0;
        loc[i] = s;
        s += v;
    }
    // inclusive wave-scan of thread totals
    int x = s;
    #pragma unroll
    for (int off = 1; off < 64; off <<= 1) {
        int y = __shfl_up(x, off, 64);
        if (lane >= off) x += y;
    }
    if (lane == 63) wtot[wv] = x;
    __syncthreads();
    if (t < 16) {
        int w0 = wtot[t];
        int xx = w0;
        #pragma unroll
        for (int off = 1; off < 16; off <<= 1) {
            int y = __shfl_up(xx, off, 16);
            if (t >= off) xx += y;
        }
        wtot[t] = xx - w0;  // exclusive wave offset
    }
    __syncthreads();
    const int tstart = wtot[wv] + (x - s);
    #pragma unroll
    for (int i = 0; i < PT; ++i) {
        int idx = base + i;
        if (idx < n) {
            int v = tstart + loc[i];
            row_start[idx] = v;
            cursor[idx] = v;
        }
    }
    if (t == 0) row_start[n] = total;  // sum of degs == e + n by construction
}

__global__ __launch_bounds__(256) void scatter_kernel(const int* __restrict__ ei, int e, int n,
                                                      int* __restrict__ cursor,
                                                      int* __restrict__ csr_src) {
    int i = blockIdx.x * 256 + threadIdx.x;
    if (i >= e + n) return;
    int s, d;
    if (i < e) { s = ei[i]; d = ei[e + i]; }
    else       { s = i - e; d = s; }       // self-loop
    int slot = atomicAdd(&cursor[d], 1);
    csr_src[slot] = s;
}

// ---------------------------------------------------------------------------
// Cast kernels: x -> fp16; W -> fp16 transposed (rows = output col, cols = k)
// ---------------------------------------------------------------------------
__global__ __launch_bounds__(256) void cast_x_kernel(const float* __restrict__ x,
                                                     __half* __restrict__ xh, int total8) {
    int t = blockIdx.x * 256 + threadIdx.x;
    if (t >= total8) return;
    size_t o = (size_t)t * 8;
    float4 a = *(const float4*)&x[o];
    float4 b = *(const float4*)&x[o + 4];
    union { __half h[8]; uint4 u; } pk;
    pk.h[0] = __float2half(a.x); pk.h[1] = __float2half(a.y);
    pk.h[2] = __float2half(a.z); pk.h[3] = __float2half(a.w);
    pk.h[4] = __float2half(b.x); pk.h[5] = __float2half(b.y);
    pk.h[6] = __float2half(b.z); pk.h[7] = __float2half(b.w);
    *(uint4*)&xh[o] = pk.u;
}

// W[K][N] -> Wt[N][K] fp16.  grid.x = N, block = 256 (K <= 256 per call)
__global__ __launch_bounds__(256) void cast_wt_kernel(const float* __restrict__ W,
                                                      __half* __restrict__ Wt, int K, int N) {
    int nrow = blockIdx.x;
    int k = threadIdx.x;
    if (k < K) Wt[(size_t)nrow * K + k] = __float2half(W[(size_t)k * N + nrow]);
}

// ---------------------------------------------------------------------------
// fp16 MFMA GEMM + fused attention logits.
// C[M,N] = A[M,K] @ B[K,N], B given TRANSPOSED as Bt[N][K].
// fp16 in, fp16 out, fp32 accumulate. K % 32 == 0, N % 64 == 0.
// CH = per-head channels; a 64-col tile covers 64/CH full heads, so each
// block computes its heads' logits exactly once from the fp32 accumulators:
//   asrc[row][head] = sum_c C[row][head*CH+c] * att_src[head][c]
// ---------------------------------------------------------------------------
template <int CH>
__global__ __launch_bounds__(256) void gemm_f16_kernel(const __half* __restrict__ A,
                                                       const __half* __restrict__ Bt,
                                                       __half* __restrict__ C,
                                                       const float* __restrict__ att_src,
                                                       const float* __restrict__ att_dst,
                                                       float* __restrict__ asrc_o,
                                                       float* __restrict__ adst_o,
                                                       int M, int K, int N) {
    constexpr int LDT = 40;  // LDS row stride in halves (32 + 8 pad)
    __shared__ __align__(16) _Float16 As[64 * LDT];
    __shared__ __align__(16) _Float16 Bs[64 * LDT];
    const int tid = threadIdx.x;
    const int bm = blockIdx.x * 64;
    const int bn = blockIdx.y * 64;
    const int w = tid >> 6;
    const int lane = tid & 63;
    const int l16 = lane & 15;
    const int quad = lane >> 4;
    const int srow = tid >> 2;        // staging row 0..63
    const int skg = tid & 3;          // staging k-group (8 halves each)

    f32x4 acc[4];
    #pragma unroll
    for (int c = 0; c < 4; ++c) acc[c] = (f32x4){0.f, 0.f, 0.f, 0.f};

    for (int k0 = 0; k0 < K; k0 += 32) {
        uint4 av = make_uint4(0, 0, 0, 0);
        if (bm + srow < M) av = *(const uint4*)&A[(size_t)(bm + srow) * K + k0 + skg * 8];
        uint4 bv = *(const uint4*)&Bt[(size_t)(bn + srow) * K + k0 + skg * 8];
        *(uint4*)&As[srow * LDT + skg * 8] = av;
        *(uint4*)&Bs[srow * LDT + skg * 8] = bv;
        __syncthreads();

        half8_t af = *(const half8_t*)&As[(w * 16 + l16) * LDT + quad * 8];
        #pragma unroll
        for (int c = 0; c < 4; ++c) {
            half8_t bf = *(const half8_t*)&Bs[(c * 16 + l16) * LDT + quad * 8];
            acc[c] = __builtin_amdgcn_mfma_f32_16x16x32_f16(af, bf, acc[c], 0, 0, 0);
        }
        __syncthreads();
    }

    // ---- C store ----
    #pragma unroll
    for (int c = 0; c < 4; ++c) {
        #pragma unroll
        for (int r = 0; r < 4; ++r) {
            int row = bm + w * 16 + quad * 4 + r;
            if (row < M)
                C[(size_t)row * N + bn + c * 16 + l16] = __float2half(acc[c][r]);
        }
    }

    // ---- fused logits from fp32 accumulators ----
    if constexpr (CH == 64) {
        const int head = blockIdx.y;
        float ps[4] = {0.f, 0.f, 0.f, 0.f}, pd[4] = {0.f, 0.f, 0.f, 0.f};
        #pragma unroll
        for (int c = 0; c < 4; ++c) {
            float av = att_src[head * 64 + c * 16 + l16];
            float dv = att_dst[head * 64 + c * 16 + l16];
            #pragma unroll
            for (int r = 0; r < 4; ++r) { ps[r] += acc[c][r] * av; pd[r] += acc[c][r] * dv; }
        }
        #pragma unroll
        for (int r = 0; r < 4; ++r) {
            #pragma unroll
            for (int off = 8; off; off >>= 1) {
                ps[r] += __shfl_down(ps[r], off, 16);
                pd[r] += __shfl_down(pd[r], off, 16);
            }
        }
        if (l16 == 0) {
            #pragma unroll
            for (int r = 0; r < 4; ++r) {
                int row = bm + w * 16 + quad * 4 + r;
                if (row < M) {
                    asrc_o[row * 8 + head] = ps[r];
                    adst_o[row * 8 + head] = pd[r];
                }
            }
        }
    } else {
        const int h0 = blockIdx.y * 2;
        float ps[2][4] = {}, pd[2][4] = {};
        #pragma unroll
        for (int c = 0; c < 4; ++c) {
            const int g = c >> 1;
            const int col = (c & 1) * 16 + l16;
            float av = att_src[(h0 + g) * 32 + col];
            float dv = att_dst[(h0 + g) * 32 + col];
            #pragma unroll
            for (int r = 0; r < 4; ++r) { ps[g][r] += acc[c][r] * av; pd[g][r] += acc[c][r] * dv; }
        }
        #pragma unroll
        for (int g = 0; g < 2; ++g)
            #pragma unroll
            for (int r = 0; r < 4; ++r) {
                #pragma unroll
                for (int off = 8; off; off >>= 1) {
                    ps[g][r] += __shfl_down(ps[g][r], off, 16);
                    pd[g][r] += __shfl_down(pd[g][r], off, 16);
                }
            }
        if (l16 == 0) {
            #pragma unroll
            for (int g = 0; g < 2; ++g)
                #pragma unroll
                for (int r = 0; r < 4; ++r) {
                    int row = bm + w * 16 + quad * 4 + r;
                    if (row < M) {
                        asrc_o[row * 8 + h0 + g] = ps[g][r];
                        adst_o[row * 8 + h0 + g] = pd[g][r];
                    }
                }
        }
    }
}

// ---------------------------------------------------------------------------
// Aggregation v8: one WAVE per (dst, head), blockIdx = dst*8 + head (XCD
// locality: head h -> XCD h, per-XCD h-slice 2.56 MB -> L2-resident).
// v8 vs v7: (offset, exp) packed into one uint2 -> single ds_write_b64 /
// ds_read_b64 per edge (was 2+2 b32 ops).
// ---------------------------------------------------------------------------
template <int CH>
__global__ __launch_bounds__(64) void aggregate_kernel(const __half* __restrict__ h,
                                                       const float* __restrict__ asrc,
                                                       const float* __restrict__ adst,
                                                       const int* __restrict__ row_start,
                                                       const int* __restrict__ csr_src,
                                                       __half* __restrict__ partial) {
    constexpr int F = 8 * CH;
    constexpr int TPE = CH / 8;          // lanes per edge: 8 (CH=64) / 4 (CH=32)
    constexpr int NSUB = 64 / TPE;       // edges in flight: 8 / 16
    constexpr int UNR = (CH == 64) ? 4 : 2;  // unrolled edge-groups per step
    constexpr int MAXD = 128;
    __shared__ uint2 s_oe[MAXD];         // .x = byte offset j*F*2, .y = exp bits
    __shared__ float s_part[NSUB * CH];  // 512 floats
    const int b = blockIdx.x;
    const int head = b & 7;
    const int i = b >> 3;
    const int lane = threadIdx.x;
    const int start = row_start[i];
    const int deg = row_start[i + 1] - start;
    const float ad = adst[i * 8 + head];

    const int sub = lane / TPE;
    const int c0 = (lane % TPE) * 8;
    const char* __restrict__ hb = (const char*)h + (head * CH + c0) * 2;
    float acc[8];
    #pragma unroll
    for (int c = 0; c < 8; ++c) acc[c] = 0.f;
    float dinv;

    if (deg <= MAXD) {
        // ---- phase 1: e -> exp -> LDS (packed with offset), partial sum ----
        float lsum = 0.f;
        for (int k = lane; k < deg; k += 64) {
            int j = csr_src[start + k];
            float e = asrc[j * 8 + head] + ad;
            e = e > 0.f ? e : 0.2f * e;
            float ex = __expf(e);       // fp32 exp: range-safe, no max needed
            s_oe[k] = make_uint2((unsigned)(j * (F * 2)), __float_as_uint(ex));
            lsum += ex;
        }
        #pragma unroll
        for (int off = 32; off; off >>= 1) lsum += __shfl_down(lsum, off, 64);
        dinv = 1.0f / __shfl(lsum, 0, 64);
        __syncthreads();

        // ---- phase 3: gather head-slice, UNR independent 16B loads ----
        int k = sub;
        for (; k + (UNR - 1) * NSUB < deg; k += UNR * NSUB) {
            uint2 oe[UNR];
            uint4 vv[UNR];
            #pragma unroll
            for (int u = 0; u < UNR; ++u) oe[u] = s_oe[k + u * NSUB];
            #pragma unroll
            for (int u = 0; u < UNR; ++u)
                vv[u] = *(const uint4*)(hb + oe[u].x);
            #pragma unroll
            for (int u = 0; u < UNR; ++u) {
                const float ww = __uint_as_float(oe[u].y);
                const __half* hv = (const __half*)&vv[u];
                #pragma unroll
                for (int c = 0; c < 8; ++c) acc[c] += ww * __half2float(hv[c]);
            }
        }
        for (; k < deg; k += NSUB) {
            uint2 oe = s_oe[k];
            uint4 v = *(const uint4*)(hb + oe.x);
            const float wgt = __uint_as_float(oe.y);
            const __half* hv = (const __half*)&v;
            #pragma unroll
            for (int c = 0; c < 8; ++c) acc[c] += wgt * __half2float(hv[c]);
        }
    } else {
        // ---- fallback (deg > MAXD): two-pass streaming, no LDS edge cache ----
        float lsum = 0.f;
        for (int k = lane; k < deg; k += 64) {
            int j = csr_src[start + k];
            float e = asrc[j * 8 + head] + ad;
            e = e > 0.f ? e : 0.2f * e;
            lsum += __expf(e);
        }
        #pragma unroll
        for (int off = 32; off; off >>= 1) lsum += __shfl_down(lsum, off, 64);
        dinv = 1.0f / __shfl(lsum, 0, 64);
        for (int k = sub; k < deg; k += NSUB) {
            const int j = csr_src[start + k];
            float e = asrc[j * 8 + head] + ad;
            e = e > 0.f ? e : 0.2f * e;
            const float wgt = __expf(e);
            uint4 v = *(const uint4*)(hb + (size_t)j * (F * 2));
            const __half* hv = (const __half*)&v;
            #pragma unroll
            for (int c = 0; c < 8; ++c) acc[c] += wgt * __half2float(hv[c]);
        }
    }

    // ---- epilogue: reduce across edge-subsets via LDS, fp16 store ----
    *(float4*)&s_part[lane * 8] = make_float4(acc[0], acc[1], acc[2], acc[3]);
    *(float4*)&s_part[lane * 8 + 4] = make_float4(acc[4], acc[5], acc[6], acc[7]);
    __syncthreads();

    if (CH == 64) {
        float v = 0.f;
        #pragma unroll
        for (int s = 0; s < 8; ++s) v += s_part[s * CH + lane];
        partial[((size_t)i * 8 + head) * CH + lane] = __float2half(v * dinv);
    } else {
        const int c = lane & 31;
        const int sh = lane >> 5;       // 0 or 1
        float v = 0.f;
        #pragma unroll
        for (int s = 0; s < 8; ++s) v += s_part[(sh * 8 + s) * CH + c];
        v += __shfl_down(v, 32, 64);
        if (lane < 32)
            partial[((size_t)i * 8 + head) * CH + c] = __float2half(v * dinv);
    }
}

// ---------------------------------------------------------------------------
// Merge heads: out = [relu](mean_h partial + bias); fp16 or fp32 output.
// ---------------------------------------------------------------------------
template <int CH, bool RELU, bool HALF_OUT>
__global__ __launch_bounds__(256) void merge_kernel(const __half* __restrict__ partial,
                                                    const float* __restrict__ bias,
                                                    void* __restrict__ out) {
    int flat = blockIdx.x * 256 + threadIdx.x;
    int i = flat / CH;
    int c = flat % CH;
    float s = 0.f;
    #pragma unroll
    for (int h8 = 0; h8 < 8; ++h8)
        s += __half2float(partial[((size_t)i * 8 + h8) * CH + c]);
    s = s * 0.125f + bias[c];
    if (RELU) s = fmaxf(s, 0.f);
    if (HALF_OUT) ((__half*)out)[flat] = __float2half(s);
    else          ((float*)out)[flat] = s;
}

// ---------------------------------------------------------------------------
// Launch
// ---------------------------------------------------------------------------
extern "C" void kernel_launch(void* const* d_in, const int* in_sizes, int n_in,
                              void* d_out, int out_size, void* d_ws, size_t ws_size,
                              hipStream_t stream) {
    const float* x   = (const float*)d_in[0];
    const int*   ei  = (const int*)d_in[1];
    const float* W1  = (const float*)d_in[2];
    const float* as1 = (const float*)d_in[3];
    const float* ad1 = (const float*)d_in[4];
    const float* b1  = (const float*)d_in[5];
    const float* W2  = (const float*)d_in[6];
    const float* as2 = (const float*)d_in[7];
    const float* ad2 = (const float*)d_in[8];
    const float* b2  = (const float*)d_in[9];

    const int n = N_NODES;
    const int e = E_EDGES;

    // ---- workspace layout (partial region also hosts xh/w1t early on) ----
    char* w = (char*)d_ws;
    __half* partial = (__half*)w;                           // 20.48 MB
    __half* xh      = (__half*)w;                           // alias: 10.24 MB
    __half* w1t     = (__half*)(w + 11u * 1024 * 1024);     // alias: +256 KB
    w += (size_t)n * 8 * 64 * 2;
    __half* h_buf = (__half*)w; w += (size_t)n * 512 * 2;   // 20.48 MB
    __half* y1    = (__half*)w; w += (size_t)n * 64 * 2;    // 2.56 MB
    __half* w2t   = (__half*)w; w += 256 * 64 * 2;
    float* asrc   = (float*)w; w += (size_t)n * 8 * 4;
    float* adst   = (float*)w; w += (size_t)n * 8 * 4;
    int* deg       = (int*)w; w += (size_t)n * 4;
    int* row_start = (int*)w; w += (size_t)(n + 1) * 4;
    int* cursor    = (int*)w; w += (size_t)n * 4;
    int* csr_src   = (int*)w; w += (size_t)(e + n) * 4;

    // ---- CSR build (graph identical for both layers) ----
    init_deg_kernel<<<(n + 255) / 256, 256, 0, stream>>>(deg, n);
    count_deg_kernel<<<(e + 255) / 256, 256, 0, stream>>>(ei, e, deg);
    scan_kernel<<<1, 1024, 0, stream>>>(deg, row_start, cursor, n, e + n);
    scatter_kernel<<<(e + n + 255) / 256, 256, 0, stream>>>(ei, e, n, cursor, csr_src);

    // ---- casts ----
    cast_x_kernel<<<(n * 256 / 8 + 255) / 256, 256, 0, stream>>>(x, xh, n * 256 / 8);
    cast_wt_kernel<<<512, 256, 0, stream>>>(W1, w1t, 256, 512);
    cast_wt_kernel<<<256, 256, 0, stream>>>(W2, w2t, 64, 256);

    // ---- Layer 1 (logits fused into GEMM epilogue) ----
    gemm_f16_kernel<64><<<dim3((n + 63) / 64, 8), 256, 0, stream>>>(
        xh, w1t, h_buf, as1, ad1, asrc, adst, n, 256, 512);
    aggregate_kernel<64><<<n * 8, 64, 0, stream>>>(h_buf, asrc, adst, row_start,
                                                   csr_src, partial);   // clobbers xh/w1t (dead)
    merge_kernel<64, true, true><<<n * 64 / 256, 256, 0, stream>>>(partial, b1, y1);

    // ---- Layer 2 ----
    gemm_f16_kernel<32><<<dim3((n + 63) / 64, 4), 256, 0, stream>>>(
        y1, w2t, h_buf, as2, ad2, asrc, adst, n, 64, 256);
    aggregate_kernel<32><<<n * 8, 64, 0, stream>>>(h_buf, asrc, adst, row_start,
                                                   csr_src, partial);
    merge_kernel<32, false, false><<<n * 32 / 256, 256, 0, stream>>>(partial, b2, (float*)d_out);
}